// Round 2
// baseline (45409.134 us; speedup 1.0000x reference)
//
#include <hip/hip_runtime.h>
#include <cmath>

#define kB 256
#define kS 512
#define kI 128
#define kH 256

// workspace layout (float offsets)
#define WS_H   0        // ping-pong h: 2 * 256*256
#define WS_C   131072   // c: 256*256
#define WS_BE  196608   // combined encoder bias: 4*256
#define WS_BD  197632   // combined decoder bias: 4*256
#define WS_WDC 198656   // combined decoder gate weights: 4*256*256
#define WS_CNT 460800   // barrier counter (1 unsigned)

#define NBLK 256u

__device__ __forceinline__ float sigmoidf_(float z) {
  return 1.0f / (1.0f + expf(-z));
}

// monotonic software grid barrier: each block's thread0 arrives once, spins
// until all NBLK blocks of this epoch have arrived. Counter never resets
// within a launch (re-zeroed by prep_kernel each kernel_launch call).
__device__ __forceinline__ void gbar(unsigned* cnt, unsigned target) {
  __syncthreads();                       // all waves drain their stores (vmcnt(0) before s_barrier)
  if (threadIdx.x == 0) {
    __threadfence();                     // release: push block's writes device-visible
    __hip_atomic_fetch_add(cnt, 1u, __ATOMIC_RELAXED, __HIP_MEMORY_SCOPE_AGENT);
    while (__hip_atomic_load(cnt, __ATOMIC_RELAXED, __HIP_MEMORY_SCOPE_AGENT) < target) {
      __builtin_amdgcn_s_sleep(2);
    }
    __threadfence();                     // acquire: invalidate caches so block reads fresh h
  }
  __syncthreads();
}

__global__ void prep_kernel(const float* __restrict__ enc_bx,
                            const float* __restrict__ enc_bh,
                            const float* __restrict__ enc_b,
                            const float* __restrict__ dec_Wx,
                            const float* __restrict__ dec_Wh,
                            const float* __restrict__ dec_bx,
                            const float* __restrict__ dec_bh,
                            const float* __restrict__ dec_b,
                            float* __restrict__ ws) {
  int gid = blockIdx.x * blockDim.x + threadIdx.x;
  int stride = gridDim.x * blockDim.x;
  float* h   = ws + WS_H;
  float* c   = ws + WS_C;
  float* be  = ws + WS_BE;
  float* bd  = ws + WS_BD;
  float* wdc = ws + WS_WDC;
  // decoder input==hidden -> combine weights once
  for (int i = gid; i < 4 * kH * kH; i += stride) wdc[i] = dec_Wx[i] + dec_Wh[i];
  for (int i = gid; i < 4 * kH; i += stride) {
    be[i] = enc_bx[i] + enc_bh[i] + enc_b[i];
    bd[i] = dec_bx[i] + dec_bh[i] + dec_b[i];
  }
  for (int i = gid; i < 2 * kB * kH; i += stride) h[i] = 0.0f;
  for (int i = gid; i < kB * kH; i += stride) c[i] = 0.0f;
  if (gid == 0) *(unsigned*)(ws + WS_CNT) = 0u;
}

// 256 blocks = 16 b-tiles x 16 hh-tiles; 256 threads; thread = (bl=tid&15, hl=tid>>4)
// Each thread owns one (b, hh): all 4 gate dot products + pointwise LSTM update.
// One software grid barrier per timestep (h ping-pong; c is owner-private).
__launch_bounds__(256)
__global__ void lstm_kernel(const float* __restrict__ x,
                            const float* __restrict__ enc_Wx,
                            const float* __restrict__ enc_Wh,
                            const float* __restrict__ rec_W,
                            const float* __restrict__ rec_b,
                            float* __restrict__ out,
                            float* __restrict__ ws) {
  float* hbuf = ws + WS_H;
  float* cbuf = ws + WS_C;
  const float* be  = ws + WS_BE;
  const float* bd  = ws + WS_BD;
  const float* wdc = ws + WS_WDC;
  unsigned* cnt = (unsigned*)(ws + WS_CNT);

  const int bt = blockIdx.x >> 4;
  const int ht = blockIdx.x & 15;
  const int b0 = bt << 4;
  const int hh0 = ht << 4;
  const int tid = threadIdx.x;
  const int bl = tid & 15;
  const int hl = tid >> 4;
  const int b = b0 + bl;
  const int hh = hh0 + hl;

  // A-tile: 16 rows x up to 384 cols, stride 388 (388%32==4 -> 2-way LDS conflict = free)
  __shared__ float As[16 * 388];
  __shared__ float red[16][17];
  __shared__ float maskS[16];

  const float* arow = &As[bl * 388];
  int cur = 0;
  unsigned bar = 0;

  // ---------------- encoder: 512 steps ----------------
  for (int t = 0; t < kS; ++t) {
    // stage A = [x_t (128) | h (256)] for our 16 b-rows
    for (int idx = tid; idx < 16 * kI; idx += 256) {
      int r = idx >> 7, ci2 = idx & (kI - 1);
      As[r * 388 + ci2] = x[(size_t)(b0 + r) * (kS * kI) + (size_t)t * kI + ci2];
    }
    for (int idx = tid; idx < 16 * kH; idx += 256) {
      int r = idx >> 8, ci2 = idx & (kH - 1);
      As[r * 388 + kI + ci2] = hbuf[cur * (kB * kH) + (b0 + r) * kH + ci2];
    }
    __syncthreads();
    // silence mask: ||x_t[b,:]||^2 > THR^2, from the staged x part
    {
      int r = tid >> 4, sub = tid & 15;
      float ss = 0.0f;
#pragma unroll
      for (int q = 0; q < 8; ++q) { float v = As[r * 388 + sub * 8 + q]; ss += v * v; }
      red[r][sub] = ss;
    }
    __syncthreads();
    if (tid < 16) {
      float ss = 0.0f;
#pragma unroll
      for (int q = 0; q < 16; ++q) ss += red[tid][q];
      maskS[tid] = (ss > 1e-6f) ? 1.0f : 0.0f;
    }

    float accf = 0.f, acci = 0.f, acco = 0.f, accc = 0.f;
    {  // x @ Wx^T part, K=128
      const float* wf = enc_Wx + (0 * kH + hh) * kI;
      const float* wi = enc_Wx + (1 * kH + hh) * kI;
      const float* wo = enc_Wx + (2 * kH + hh) * kI;
      const float* wc = enc_Wx + (3 * kH + hh) * kI;
      for (int k = 0; k < kI; k += 4) {
        float4 a  = *(const float4*)(arow + k);
        float4 f4 = *(const float4*)(wf + k);
        float4 i4 = *(const float4*)(wi + k);
        float4 o4 = *(const float4*)(wo + k);
        float4 c4 = *(const float4*)(wc + k);
        accf += a.x * f4.x + a.y * f4.y + a.z * f4.z + a.w * f4.w;
        acci += a.x * i4.x + a.y * i4.y + a.z * i4.z + a.w * i4.w;
        acco += a.x * o4.x + a.y * o4.y + a.z * o4.z + a.w * o4.w;
        accc += a.x * c4.x + a.y * c4.y + a.z * c4.z + a.w * c4.w;
      }
    }
    {  // h @ Wh^T part, K=256
      const float* wf = enc_Wh + (0 * kH + hh) * kH;
      const float* wi = enc_Wh + (1 * kH + hh) * kH;
      const float* wo = enc_Wh + (2 * kH + hh) * kH;
      const float* wc = enc_Wh + (3 * kH + hh) * kH;
      for (int k = 0; k < kH; k += 4) {
        float4 a  = *(const float4*)(arow + kI + k);
        float4 f4 = *(const float4*)(wf + k);
        float4 i4 = *(const float4*)(wi + k);
        float4 o4 = *(const float4*)(wo + k);
        float4 c4 = *(const float4*)(wc + k);
        accf += a.x * f4.x + a.y * f4.y + a.z * f4.z + a.w * f4.w;
        acci += a.x * i4.x + a.y * i4.y + a.z * i4.z + a.w * i4.w;
        acco += a.x * o4.x + a.y * o4.y + a.z * o4.z + a.w * o4.w;
        accc += a.x * c4.x + a.y * c4.y + a.z * c4.z + a.w * c4.w;
      }
    }
    __syncthreads();  // maskS ready
    float mb = maskS[bl];
    float fg  = sigmoidf_(accf + be[0 * kH + hh]);
    float ig  = sigmoidf_(acci + be[1 * kH + hh]);
    float og  = sigmoidf_(acco + be[2 * kH + hh]);
    float ctl = tanhf(accc + be[3 * kH + hh]);
    int chix = b * kH + hh;
    float cold = cbuf[chix];
    float cnew = (fg + ig) * cold + mb * (ig * ctl);
    cbuf[chix] = cnew;
    hbuf[(cur ^ 1) * (kB * kH) + chix] = og * tanhf(cnew);
    ++bar;
    gbar(cnt, bar * NBLK);
    cur ^= 1;
  }

  // ---------------- decoder: 512 steps ----------------
  for (int t = 0; t < kS; ++t) {
    // stage A = h_{t-1} for our 16 b-rows
    for (int idx = tid; idx < 16 * kH; idx += 256) {
      int r = idx >> 8, ci2 = idx & (kH - 1);
      As[r * 388 + ci2] = hbuf[cur * (kB * kH) + (b0 + r) * kH + ci2];
    }
    __syncthreads();
    // silence mask on decoder input (= h_{t-1})
    {
      int r = tid >> 4, sub = tid & 15;
      float ss = 0.0f;
#pragma unroll
      for (int q = 0; q < 16; ++q) { float v = As[r * 388 + sub * 16 + q]; ss += v * v; }
      red[r][sub] = ss;
    }
    __syncthreads();
    if (tid < 16) {
      float ss = 0.0f;
#pragma unroll
      for (int q = 0; q < 16; ++q) ss += red[tid][q];
      maskS[tid] = (ss > 1e-6f) ? 1.0f : 0.0f;
    }

    float accf = 0.f, acci = 0.f, acco = 0.f, accc = 0.f;
    {  // h @ (Wx+Wh)^T, K=256
      const float* wf = wdc + (0 * kH + hh) * kH;
      const float* wi = wdc + (1 * kH + hh) * kH;
      const float* wo = wdc + (2 * kH + hh) * kH;
      const float* wc = wdc + (3 * kH + hh) * kH;
      for (int k = 0; k < kH; k += 4) {
        float4 a  = *(const float4*)(arow + k);
        float4 f4 = *(const float4*)(wf + k);
        float4 i4 = *(const float4*)(wi + k);
        float4 o4 = *(const float4*)(wo + k);
        float4 c4 = *(const float4*)(wc + k);
        accf += a.x * f4.x + a.y * f4.y + a.z * f4.z + a.w * f4.w;
        acci += a.x * i4.x + a.y * i4.y + a.z * i4.z + a.w * i4.w;
        acco += a.x * o4.x + a.y * o4.y + a.z * o4.z + a.w * o4.w;
        accc += a.x * c4.x + a.y * c4.y + a.z * c4.z + a.w * c4.w;
      }
    }
    // reconstruct output of PREVIOUS h (h_{t-1} is in LDS): out[:, t-1, :]
    float racc = 0.0f;
    if (ht < 8) {  // hh in [0,128) doubles as the rec output column
      const float* wr = rec_W + hh * kH;
      for (int k = 0; k < kH; k += 4) {
        float4 a  = *(const float4*)(arow + k);
        float4 w4 = *(const float4*)(wr + k);
        racc += a.x * w4.x + a.y * w4.y + a.z * w4.z + a.w * w4.w;
      }
    }
    __syncthreads();
    float mb = maskS[bl];
    float fg  = sigmoidf_(accf + bd[0 * kH + hh]);
    float ig  = sigmoidf_(acci + bd[1 * kH + hh]);
    float og  = sigmoidf_(acco + bd[2 * kH + hh]);
    float ctl = tanhf(accc + bd[3 * kH + hh]);
    int chix = b * kH + hh;
    float cold = cbuf[chix];
    float cnew = (fg + ig) * cold + mb * (ig * ctl);
    cbuf[chix] = cnew;
    hbuf[(cur ^ 1) * (kB * kH) + chix] = og * tanhf(cnew);
    if (ht < 8 && t > 0)
      out[(size_t)b * (kS * kI) + (size_t)(t - 1) * kI + hh] = racc + rec_b[hh];
    ++bar;
    gbar(cnt, bar * NBLK);
    cur ^= 1;
  }

  // ---------------- final rec: out[:, S-1, :] from h_{S-1} ----------------
  if (ht < 8) {
    for (int idx = tid; idx < 16 * kH; idx += 256) {
      int r = idx >> 8, ci2 = idx & (kH - 1);
      As[r * 388 + ci2] = hbuf[cur * (kB * kH) + (b0 + r) * kH + ci2];
    }
    __syncthreads();
    float racc = 0.0f;
    const float* wr = rec_W + hh * kH;
    for (int k = 0; k < kH; k += 4) {
      float4 a  = *(const float4*)(arow + k);
      float4 w4 = *(const float4*)(wr + k);
      racc += a.x * w4.x + a.y * w4.y + a.z * w4.z + a.w * w4.w;
    }
    out[(size_t)b * (kS * kI) + (size_t)(kS - 1) * kI + hh] = racc + rec_b[hh];
  }
}

extern "C" void kernel_launch(void* const* d_in, const int* in_sizes, int n_in,
                              void* d_out, int out_size, void* d_ws, size_t ws_size,
                              hipStream_t stream) {
  const float* x      = (const float*)d_in[0];
  const float* enc_Wx = (const float*)d_in[1];
  const float* enc_bx = (const float*)d_in[2];
  const float* enc_Wh = (const float*)d_in[3];
  const float* enc_bh = (const float*)d_in[4];
  const float* enc_b  = (const float*)d_in[5];
  const float* dec_Wx = (const float*)d_in[6];
  const float* dec_bx = (const float*)d_in[7];
  const float* dec_Wh = (const float*)d_in[8];
  const float* dec_bh = (const float*)d_in[9];
  const float* dec_b  = (const float*)d_in[10];
  const float* rec_W  = (const float*)d_in[11];
  const float* rec_b  = (const float*)d_in[12];
  float* out = (float*)d_out;
  float* ws  = (float*)d_ws;

  hipLaunchKernelGGL(prep_kernel, dim3(256), dim3(256), 0, stream,
                     enc_bx, enc_bh, enc_b, dec_Wx, dec_Wh, dec_bx, dec_bh, dec_b, ws);

  hipLaunchKernelGGL(lstm_kernel, dim3(NBLK), dim3(256), 0, stream,
                     x, enc_Wx, enc_Wh, rec_W, rec_b, out, ws);
}

// Round 6
// 15020.216 us; speedup vs baseline: 3.0232x; 3.0232x over previous
//
#include <hip/hip_runtime.h>
#include <cmath>

#define kB 256
#define kS 512
#define kI 128
#define kH 256

typedef __attribute__((ext_vector_type(8))) short short8;
typedef __attribute__((ext_vector_type(4))) float f32x4;

#define AS_STRIDE 408  // bf16 elems; row stride 816B

// ws layout (bytes):
//  [0, 16K)        flags: u32[16 grp][16 slice], stride 16 u32 (64B/flag)
//  [16K, 16K+512K) hx: f32 bits as u32 [2 parity][16 grp][16 b][256]
#define WS_FLAG_BYTES 16384
#define WS_HX_U32     (2 * 16 * 16 * 256)

__device__ __forceinline__ float sigmoidf_(float z) { return 1.0f / (1.0f + expf(-z)); }

// f32 -> bf16 RNE
__device__ __forceinline__ unsigned short f2b(float f) {
  unsigned u = __builtin_bit_cast(unsigned, f);
  unsigned r = (u + 0x7fffu + ((u >> 16) & 1u)) >> 16;
  return (unsigned short)r;
}
__device__ __forceinline__ float b2f(unsigned short s) {
  unsigned u = ((unsigned)s) << 16;
  return __builtin_bit_cast(float, u);
}
__device__ __forceinline__ void bsplit2(float f, unsigned short& h_, unsigned short& l_) {
  h_ = f2b(f);
  l_ = f2b(f - b2f(h_));
}
__device__ __forceinline__ void bsplit3(float f, unsigned short& h_, unsigned short& m_, unsigned short& l_) {
  h_ = f2b(f);
  float r1 = f - b2f(h_);
  m_ = f2b(r1);
  l_ = f2b(r1 - b2f(m_));
}

// spin until *flp >= s, then establish ACQUIRE ordering so subsequent hx loads
// observe everything before the writer's RELEASE flag store (message-passing).
__device__ __forceinline__ void wait_flag(const unsigned* flp, unsigned s) {
  while (__hip_atomic_load(flp, __ATOMIC_RELAXED, __HIP_MEMORY_SCOPE_SYSTEM) < s)
    __builtin_amdgcn_s_sleep(1);
  (void)__hip_atomic_load(flp, __ATOMIC_ACQUIRE, __HIP_MEMORY_SCOPE_SYSTEM);
}

__launch_bounds__(256, 1)
__global__ void lstm_mfma(const float* __restrict__ x,
                          const float* __restrict__ enc_Wx, const float* __restrict__ enc_bx,
                          const float* __restrict__ enc_Wh, const float* __restrict__ enc_bh,
                          const float* __restrict__ enc_b,
                          const float* __restrict__ dec_Wx, const float* __restrict__ dec_bx,
                          const float* __restrict__ dec_Wh, const float* __restrict__ dec_bh,
                          const float* __restrict__ dec_b,
                          const float* __restrict__ rec_W, const float* __restrict__ rec_b,
                          float* __restrict__ out,
                          unsigned* __restrict__ flags,
                          unsigned* __restrict__ hx) {
  __shared__ __align__(16) short As_h[16 * AS_STRIDE];
  __shared__ __align__(16) short As_m[16 * AS_STRIDE];
  __shared__ __align__(16) short As_l[16 * AS_STRIDE];
  __shared__ float g_scr[4 * 16 * 17];
  __shared__ float r_scr[4 * 16 * 17];
  __shared__ float red[16][16];
  __shared__ float maskS[16];

  const int tid = threadIdx.x;
  const int bt = blockIdx.x >> 4;   // b-group (16 rows each)
  const int ht = blockIdx.x & 15;   // hh-slice (16 hh each)
  const int b0 = bt << 4, hh0 = ht << 4;
  const int w  = tid >> 6;          // wave id == gate id (f,i,o,c~)
  const int l  = tid & 63;
  const int fr = l & 15;            // MFMA frag row/col
  const int gq = l >> 4;            // MFMA k-subgroup
  const int b  = tid >> 4;          // staging/cell: local b row
  const int q  = tid & 15;          // staging slice / cell hh-local
  const int hh = hh0 + q;

  // ---- combined biases ----
  float be0 = enc_bx[0*kH+hh] + enc_bh[0*kH+hh] + enc_b[0*kH+hh];
  float be1 = enc_bx[1*kH+hh] + enc_bh[1*kH+hh] + enc_b[1*kH+hh];
  float be2 = enc_bx[2*kH+hh] + enc_bh[2*kH+hh] + enc_b[2*kH+hh];
  float be3 = enc_bx[3*kH+hh] + enc_bh[3*kH+hh] + enc_b[3*kH+hh];
  float bd0 = dec_bx[0*kH+hh] + dec_bh[0*kH+hh] + dec_b[0*kH+hh];
  float bd1 = dec_bx[1*kH+hh] + dec_bh[1*kH+hh] + dec_b[1*kH+hh];
  float bd2 = dec_bx[2*kH+hh] + dec_bh[2*kH+hh] + dec_b[2*kH+hh];
  float bd3 = dec_bx[3*kH+hh] + dec_bh[3*kH+hh] + dec_b[3*kH+hh];
  float recb = (ht < 8) ? rec_b[hh0 + q] : 0.0f;
  float creg = 0.0f;  // cell state, fp32, register-resident

  // ---- encoder weight fragments (bf16 3-way split), K=384 cat [Wx|Wh] ----
  short8 wfh[12], wfm[12], wfl[12];
#pragma unroll
  for (int kst = 0; kst < 12; ++kst) {
    int k = kst * 32 + gq * 8;
    const float* src = (k < 128)
        ? (enc_Wx + ((size_t)(w * kH) + hh0 + fr) * kI + k)
        : (enc_Wh + ((size_t)(w * kH) + hh0 + fr) * kH + (k - 128));
    short8 hi, mi, lo;
#pragma unroll
    for (int j = 0; j < 8; ++j) {
      unsigned short h_, m_, l_;
      bsplit3(src[j], h_, m_, l_);
      hi[j] = (short)h_; mi[j] = (short)m_; lo[j] = (short)l_;
    }
    wfh[kst] = hi; wfm[kst] = mi; wfl[kst] = lo;
  }

  const unsigned* flp = flags + (bt * 16 + q) * 16;  // flag of the slice this thread stages
  unsigned* flown = flags + (bt * 16 + ht) * 16;     // this block's own flag

  // ================= encoder: 512 steps =================
  for (int s = 0; s < kS; ++s) {
    const int par = s & 1;
    // stage h slice q into As[.][128+16q]: f32 -> 3-way bf16 split (exact path)
    {
      wait_flag(flp, (unsigned)s);
      size_t hxi = (((size_t)(par * 16 + bt) * 16 + b) * 256) + q * 16;
      float v[16];
#pragma unroll
      for (int i = 0; i < 16; ++i)
        v[i] = __builtin_bit_cast(float, __hip_atomic_load(hx + hxi + i, __ATOMIC_RELAXED, __HIP_MEMORY_SCOPE_SYSTEM));
      short8 H0, H1, M0, M1, L0, L1;
#pragma unroll
      for (int j = 0; j < 16; ++j) {
        unsigned short h_, m_, l_;
        bsplit3(v[j], h_, m_, l_);
        if (j < 8) { H0[j] = (short)h_; M0[j] = (short)m_; L0[j] = (short)l_; }
        else       { H1[j-8] = (short)h_; M1[j-8] = (short)m_; L1[j-8] = (short)l_; }
      }
      *(short8*)(As_h + b * AS_STRIDE + 128 + q * 16)     = H0;
      *(short8*)(As_h + b * AS_STRIDE + 128 + q * 16 + 8) = H1;
      *(short8*)(As_m + b * AS_STRIDE + 128 + q * 16)     = M0;
      *(short8*)(As_m + b * AS_STRIDE + 128 + q * 16 + 8) = M1;
      *(short8*)(As_l + b * AS_STRIDE + 128 + q * 16)     = L0;
      *(short8*)(As_l + b * AS_STRIDE + 128 + q * 16 + 8) = L1;
    }
    // stage x chunk (q<8) as bf16x3 + silence-mask partials (exact f32)
    if (q < 8) {
      const float* xp = x + ((size_t)(b0 + b) * kS + s) * kI + q * 16;
      float arr[16];
      *(float4*)(arr + 0)  = *(const float4*)(xp + 0);
      *(float4*)(arr + 4)  = *(const float4*)(xp + 4);
      *(float4*)(arr + 8)  = *(const float4*)(xp + 8);
      *(float4*)(arr + 12) = *(const float4*)(xp + 12);
      float ss = 0.f;
      short8 H0, H1, M0, M1, L0, L1;
#pragma unroll
      for (int j = 0; j < 16; ++j) {
        float v = arr[j];
        ss += v * v;
        unsigned short h_, m_, l_;
        bsplit3(v, h_, m_, l_);
        if (j < 8) { H0[j] = (short)h_; M0[j] = (short)m_; L0[j] = (short)l_; }
        else       { H1[j-8] = (short)h_; M1[j-8] = (short)m_; L1[j-8] = (short)l_; }
      }
      *(short8*)(As_h + b * AS_STRIDE + q * 16)     = H0;
      *(short8*)(As_h + b * AS_STRIDE + q * 16 + 8) = H1;
      *(short8*)(As_m + b * AS_STRIDE + q * 16)     = M0;
      *(short8*)(As_m + b * AS_STRIDE + q * 16 + 8) = M1;
      *(short8*)(As_l + b * AS_STRIDE + q * 16)     = L0;
      *(short8*)(As_l + b * AS_STRIDE + q * 16 + 8) = L1;
      red[b][q] = ss;
    }
    __syncthreads();
    if (tid < 16) {
      float ss = 0.f;
#pragma unroll
      for (int j = 0; j < 8; ++j) ss += red[tid][j];
      maskS[tid] = (ss > 1e-6f) ? 1.0f : 0.0f;
    }
    // gate GEMM: K=384, 6-term bf16 scheme (all cross terms >= 2^-27)
    f32x4 a0 = {0.f,0.f,0.f,0.f}, a1 = a0, a2 = a0, a3 = a0, a4 = a0, a5 = a0;
#pragma unroll
    for (int kst = 0; kst < 12; ++kst) {
      const short8 ah = *(const short8*)(As_h + fr * AS_STRIDE + kst * 32 + gq * 8);
      const short8 am = *(const short8*)(As_m + fr * AS_STRIDE + kst * 32 + gq * 8);
      const short8 al = *(const short8*)(As_l + fr * AS_STRIDE + kst * 32 + gq * 8);
      a0 = __builtin_amdgcn_mfma_f32_16x16x32_bf16(ah, wfh[kst], a0, 0, 0, 0);
      a1 = __builtin_amdgcn_mfma_f32_16x16x32_bf16(ah, wfm[kst], a1, 0, 0, 0);
      a2 = __builtin_amdgcn_mfma_f32_16x16x32_bf16(am, wfh[kst], a2, 0, 0, 0);
      a3 = __builtin_amdgcn_mfma_f32_16x16x32_bf16(ah, wfl[kst], a3, 0, 0, 0);
      a4 = __builtin_amdgcn_mfma_f32_16x16x32_bf16(am, wfm[kst], a4, 0, 0, 0);
      a5 = __builtin_amdgcn_mfma_f32_16x16x32_bf16(al, wfh[kst], a5, 0, 0, 0);
    }
    f32x4 d = (((a5 + a4) + a3) + (a2 + a1)) + a0;
#pragma unroll
    for (int i = 0; i < 4; ++i) g_scr[(w * 16 + gq * 4 + i) * 17 + fr] = d[i];
    __syncthreads();
    // cell update (thread owns (b, hh)); publish h as f32 bits
    {
      float gf = g_scr[(0 * 16 + b) * 17 + q] + be0;
      float gi = g_scr[(1 * 16 + b) * 17 + q] + be1;
      float go = g_scr[(2 * 16 + b) * 17 + q] + be2;
      float gc = g_scr[(3 * 16 + b) * 17 + q] + be3;
      float m  = maskS[b];
      float f_ = sigmoidf_(gf), i_ = sigmoidf_(gi), o_ = sigmoidf_(go);
      float ct = tanhf(gc);
      creg = (f_ + i_) * creg + m * (i_ * ct);
      float hval = o_ * tanhf(creg);
      size_t wi = (((size_t)(((s + 1) & 1) * 16 + bt) * 16 + b) * 256) + hh0 + q;
      __hip_atomic_store(hx + wi, __builtin_bit_cast(unsigned, hval),
                         __ATOMIC_RELAXED, __HIP_MEMORY_SCOPE_SYSTEM);
    }
    __syncthreads();
    if (tid == 0)  // RELEASE: orders all block's hx stores before the flag
      __hip_atomic_store(flown, (unsigned)(s + 1), __ATOMIC_RELEASE, __HIP_MEMORY_SCOPE_SYSTEM);
  }

  // ---- decoder weights: wdc = dec_Wx + dec_Wh (K=256, 3-way); rec 2-way, K-split over waves ----
  short8 dwh[8], dwm[8], dwl[8];
#pragma unroll
  for (int kst = 0; kst < 8; ++kst) {
    int k = kst * 32 + gq * 8;
    const float* s1 = dec_Wx + ((size_t)(w * kH) + hh0 + fr) * kH + k;
    const float* s2 = dec_Wh + ((size_t)(w * kH) + hh0 + fr) * kH + k;
    short8 hi, mi, lo;
#pragma unroll
    for (int j = 0; j < 8; ++j) {
      unsigned short h_, m_, l_;
      bsplit3(s1[j] + s2[j], h_, m_, l_);
      hi[j] = (short)h_; mi[j] = (short)m_; lo[j] = (short)l_;
    }
    dwh[kst] = hi; dwm[kst] = mi; dwl[kst] = lo;
  }
  short8 rfh[2], rfl[2];
#pragma unroll
  for (int kk = 0; kk < 2; ++kk) {
    short8 hi = {0,0,0,0,0,0,0,0}, lo = hi;
    if (ht < 8) {
      int k = (2 * w + kk) * 32 + gq * 8;
      const float* src = rec_W + ((size_t)(hh0 + fr)) * kH + k;
#pragma unroll
      for (int j = 0; j < 8; ++j) {
        unsigned short h_, l_;
        bsplit2(src[j], h_, l_);
        hi[j] = (short)h_; lo[j] = (short)l_;
      }
    }
    rfh[kk] = hi; rfl[kk] = lo;
  }

  // ================= decoder: 512 steps =================
  for (int t = 0; t < kS; ++t) {
    const int s = kS + t;
    const int par = s & 1;
    // stage h (K=256 at offset 0), f32 -> bf16x3, mask partial exact
    {
      wait_flag(flp, (unsigned)s);
      size_t hxi = (((size_t)(par * 16 + bt) * 16 + b) * 256) + q * 16;
      float v[16];
#pragma unroll
      for (int i = 0; i < 16; ++i)
        v[i] = __builtin_bit_cast(float, __hip_atomic_load(hx + hxi + i, __ATOMIC_RELAXED, __HIP_MEMORY_SCOPE_SYSTEM));
      float ss = 0.f;
      short8 H0, H1, M0, M1, L0, L1;
#pragma unroll
      for (int j = 0; j < 16; ++j) {
        float vv = v[j];
        ss += vv * vv;
        unsigned short h_, m_, l_;
        bsplit3(vv, h_, m_, l_);
        if (j < 8) { H0[j] = (short)h_; M0[j] = (short)m_; L0[j] = (short)l_; }
        else       { H1[j-8] = (short)h_; M1[j-8] = (short)m_; L1[j-8] = (short)l_; }
      }
      *(short8*)(As_h + b * AS_STRIDE + q * 16)     = H0;
      *(short8*)(As_h + b * AS_STRIDE + q * 16 + 8) = H1;
      *(short8*)(As_m + b * AS_STRIDE + q * 16)     = M0;
      *(short8*)(As_m + b * AS_STRIDE + q * 16 + 8) = M1;
      *(short8*)(As_l + b * AS_STRIDE + q * 16)     = L0;
      *(short8*)(As_l + b * AS_STRIDE + q * 16 + 8) = L1;
      red[b][q] = ss;
    }
    __syncthreads();
    if (tid < 16) {
      float ss = 0.f;
#pragma unroll
      for (int j = 0; j < 16; ++j) ss += red[tid][j];
      maskS[tid] = (ss > 1e-6f) ? 1.0f : 0.0f;
    }
    // gate GEMM K=256, 6-term scheme
    f32x4 a0 = {0.f,0.f,0.f,0.f}, a1 = a0, a2 = a0, a3 = a0, a4 = a0, a5 = a0;
#pragma unroll
    for (int kst = 0; kst < 8; ++kst) {
      const short8 ah = *(const short8*)(As_h + fr * AS_STRIDE + kst * 32 + gq * 8);
      const short8 am = *(const short8*)(As_m + fr * AS_STRIDE + kst * 32 + gq * 8);
      const short8 al = *(const short8*)(As_l + fr * AS_STRIDE + kst * 32 + gq * 8);
      a0 = __builtin_amdgcn_mfma_f32_16x16x32_bf16(ah, dwh[kst], a0, 0, 0, 0);
      a1 = __builtin_amdgcn_mfma_f32_16x16x32_bf16(ah, dwm[kst], a1, 0, 0, 0);
      a2 = __builtin_amdgcn_mfma_f32_16x16x32_bf16(am, dwh[kst], a2, 0, 0, 0);
      a3 = __builtin_amdgcn_mfma_f32_16x16x32_bf16(ah, dwl[kst], a3, 0, 0, 0);
      a4 = __builtin_amdgcn_mfma_f32_16x16x32_bf16(am, dwm[kst], a4, 0, 0, 0);
      a5 = __builtin_amdgcn_mfma_f32_16x16x32_bf16(al, dwh[kst], a5, 0, 0, 0);
    }
    f32x4 d = (((a5 + a4) + a3) + (a2 + a1)) + a0;
#pragma unroll
    for (int i = 0; i < 4; ++i) g_scr[(w * 16 + gq * 4 + i) * 17 + fr] = d[i];
    // rec GEMM on staged h_(t-1): wave w covers ksteps {2w, 2w+1} (no amplification)
    if (ht < 8) {
      f32x4 r0 = {0.f,0.f,0.f,0.f}, r1 = r0, r2 = r0;
#pragma unroll
      for (int kk = 0; kk < 2; ++kk) {
        const short8 ah = *(const short8*)(As_h + fr * AS_STRIDE + (2 * w + kk) * 32 + gq * 8);
        const short8 am = *(const short8*)(As_m + fr * AS_STRIDE + (2 * w + kk) * 32 + gq * 8);
        r0 = __builtin_amdgcn_mfma_f32_16x16x32_bf16(ah, rfh[kk], r0, 0, 0, 0);
        r1 = __builtin_amdgcn_mfma_f32_16x16x32_bf16(ah, rfl[kk], r1, 0, 0, 0);
        r2 = __builtin_amdgcn_mfma_f32_16x16x32_bf16(am, rfh[kk], r2, 0, 0, 0);
      }
      f32x4 rd = r0 + r1 + r2;
#pragma unroll
      for (int i = 0; i < 4; ++i) r_scr[(w * 16 + gq * 4 + i) * 17 + fr] = rd[i];
    }
    __syncthreads();
    // cell update + h publish
    {
      float gf = g_scr[(0 * 16 + b) * 17 + q] + bd0;
      float gi = g_scr[(1 * 16 + b) * 17 + q] + bd1;
      float go = g_scr[(2 * 16 + b) * 17 + q] + bd2;
      float gc = g_scr[(3 * 16 + b) * 17 + q] + bd3;
      float m  = maskS[b];
      float f_ = sigmoidf_(gf), i_ = sigmoidf_(gi), o_ = sigmoidf_(go);
      float ct = tanhf(gc);
      creg = (f_ + i_) * creg + m * (i_ * ct);
      float hval = o_ * tanhf(creg);
      size_t wi = (((size_t)(((s + 1) & 1) * 16 + bt) * 16 + b) * 256) + hh0 + q;
      __hip_atomic_store(hx + wi, __builtin_bit_cast(unsigned, hval),
                         __ATOMIC_RELAXED, __HIP_MEMORY_SCOPE_SYSTEM);
    }
    // reconstruct out[:, t-1, :] from staged h_(t-1)
    if (ht < 8 && t > 0) {
      float rsum = r_scr[(0 * 16 + b) * 17 + q] + r_scr[(1 * 16 + b) * 17 + q]
                 + r_scr[(2 * 16 + b) * 17 + q] + r_scr[(3 * 16 + b) * 17 + q] + recb;
      out[((size_t)(b0 + b) * kS + (t - 1)) * kI + hh0 + q] = rsum;
    }
    __syncthreads();
    if (tid == 0)  // RELEASE
      __hip_atomic_store(flown, (unsigned)(s + 1), __ATOMIC_RELEASE, __HIP_MEMORY_SCOPE_SYSTEM);
  }

  // ================= final rec: out[:, 511, :] from h_dec_511 =================
  {
    const int s = 2 * kS;  // 1024, parity 0
    {
      wait_flag(flp, (unsigned)s);
      size_t hxi = (((size_t)(0 * 16 + bt) * 16 + b) * 256) + q * 16;
      float v[16];
#pragma unroll
      for (int i = 0; i < 16; ++i)
        v[i] = __builtin_bit_cast(float, __hip_atomic_load(hx + hxi + i, __ATOMIC_RELAXED, __HIP_MEMORY_SCOPE_SYSTEM));
      short8 H0, H1, M0, M1;
#pragma unroll
      for (int j = 0; j < 16; ++j) {
        unsigned short h_, m_, l_;
        bsplit3(v[j], h_, m_, l_);
        if (j < 8) { H0[j] = (short)h_; M0[j] = (short)m_; }
        else       { H1[j-8] = (short)h_; M1[j-8] = (short)m_; }
      }
      *(short8*)(As_h + b * AS_STRIDE + q * 16)     = H0;
      *(short8*)(As_h + b * AS_STRIDE + q * 16 + 8) = H1;
      *(short8*)(As_m + b * AS_STRIDE + q * 16)     = M0;
      *(short8*)(As_m + b * AS_STRIDE + q * 16 + 8) = M1;
    }
    __syncthreads();
    if (ht < 8) {
      f32x4 r0 = {0.f,0.f,0.f,0.f}, r1 = r0, r2 = r0;
#pragma unroll
      for (int kk = 0; kk < 2; ++kk) {
        const short8 ah = *(const short8*)(As_h + fr * AS_STRIDE + (2 * w + kk) * 32 + gq * 8);
        const short8 am = *(const short8*)(As_m + fr * AS_STRIDE + (2 * w + kk) * 32 + gq * 8);
        r0 = __builtin_amdgcn_mfma_f32_16x16x32_bf16(ah, rfh[kk], r0, 0, 0, 0);
        r1 = __builtin_amdgcn_mfma_f32_16x16x32_bf16(ah, rfl[kk], r1, 0, 0, 0);
        r2 = __builtin_amdgcn_mfma_f32_16x16x32_bf16(am, rfh[kk], r2, 0, 0, 0);
      }
      f32x4 rd = r0 + r1 + r2;
#pragma unroll
      for (int i = 0; i < 4; ++i) r_scr[(w * 16 + gq * 4 + i) * 17 + fr] = rd[i];
    }
    __syncthreads();
    if (ht < 8) {
      float rsum = r_scr[(0 * 16 + b) * 17 + q] + r_scr[(1 * 16 + b) * 17 + q]
                 + r_scr[(2 * 16 + b) * 17 + q] + r_scr[(3 * 16 + b) * 17 + q] + recb;
      out[((size_t)(b0 + b) * kS + (kS - 1)) * kI + hh0 + q] = rsum;
    }
  }
}

extern "C" void kernel_launch(void* const* d_in, const int* in_sizes, int n_in,
                              void* d_out, int out_size, void* d_ws, size_t ws_size,
                              hipStream_t stream) {
  const float* x      = (const float*)d_in[0];
  const float* enc_Wx = (const float*)d_in[1];
  const float* enc_bx = (const float*)d_in[2];
  const float* enc_Wh = (const float*)d_in[3];
  const float* enc_bh = (const float*)d_in[4];
  const float* enc_b  = (const float*)d_in[5];
  const float* dec_Wx = (const float*)d_in[6];
  const float* dec_bx = (const float*)d_in[7];
  const float* dec_Wh = (const float*)d_in[8];
  const float* dec_bh = (const float*)d_in[9];
  const float* dec_b  = (const float*)d_in[10];
  const float* rec_W  = (const float*)d_in[11];
  const float* rec_b  = (const float*)d_in[12];
  float* out = (float*)d_out;

  unsigned* flags = (unsigned*)d_ws;
  unsigned* hx = (unsigned*)((char*)d_ws + WS_FLAG_BYTES);

  hipMemsetAsync(d_ws, 0, WS_FLAG_BYTES + (size_t)WS_HX_U32 * 4, stream);

  hipLaunchKernelGGL(lstm_mfma, dim3(256), dim3(256), 0, stream,
                     x, enc_Wx, enc_bx, enc_Wh, enc_bh, enc_b,
                     dec_Wx, dec_bx, dec_Wh, dec_bh, dec_b,
                     rec_W, rec_b, out, flags, hx);
}

// Round 7
// 9375.829 us; speedup vs baseline: 4.8432x; 1.6020x over previous
//
#include <hip/hip_runtime.h>
#include <cmath>

#define kB 256
#define kS 512
#define kI 128
#define kH 256

typedef __attribute__((ext_vector_type(8))) short short8;
typedef __attribute__((ext_vector_type(4))) float f32x4;

#define AS_STRIDE 408  // bf16 elems; row stride 816B

// ws layout (bytes):
//  [0, 16K)        flags: u32[16 grp][16 slice], stride 16 u32 (64B/flag)
//  [16K, 16K+512K) hx: f32 bits as u32 [2 parity][16 grp][16 b][256]
#define WS_FLAG_BYTES 16384
#define WS_HX_U32     (2 * 16 * 16 * 256)

__device__ __forceinline__ float sigmoidf_(float z) { return 1.0f / (1.0f + expf(-z)); }

// f32 -> bf16 RNE
__device__ __forceinline__ unsigned short f2b(float f) {
  unsigned u = __builtin_bit_cast(unsigned, f);
  unsigned r = (u + 0x7fffu + ((u >> 16) & 1u)) >> 16;
  return (unsigned short)r;
}
__device__ __forceinline__ float b2f(unsigned short s) {
  unsigned u = ((unsigned)s) << 16;
  return __builtin_bit_cast(float, u);
}
__device__ __forceinline__ void bsplit2(float f, unsigned short& h_, unsigned short& l_) {
  h_ = f2b(f);
  l_ = f2b(f - b2f(h_));
}
__device__ __forceinline__ void bsplit3(float f, unsigned short& h_, unsigned short& m_, unsigned short& l_) {
  h_ = f2b(f);
  float r1 = f - b2f(h_);
  m_ = f2b(r1);
  l_ = f2b(r1 - b2f(m_));
}

// spin until *flp >= s. hx reads are system-scope (sc0sc1) loads that bypass
// L1/L2 and read the LLC directly, so no acquire/cache-invalidate is needed
// here — the producer's RELEASE (vmcnt drain + buffer_wbl2) guarantees hx is
// durable at LLC before the flag becomes visible.
__device__ __forceinline__ void wait_flag(const unsigned* flp, unsigned s) {
  while (__hip_atomic_load(flp, __ATOMIC_RELAXED, __HIP_MEMORY_SCOPE_SYSTEM) < s)
    __builtin_amdgcn_s_sleep(1);
  asm volatile("" ::: "memory");  // compiler barrier: no hoisting of hx loads
}

__launch_bounds__(256, 1)
__global__ void lstm_mfma(const float* __restrict__ x,
                          const float* __restrict__ enc_Wx, const float* __restrict__ enc_bx,
                          const float* __restrict__ enc_Wh, const float* __restrict__ enc_bh,
                          const float* __restrict__ enc_b,
                          const float* __restrict__ dec_Wx, const float* __restrict__ dec_bx,
                          const float* __restrict__ dec_Wh, const float* __restrict__ dec_bh,
                          const float* __restrict__ dec_b,
                          const float* __restrict__ rec_W, const float* __restrict__ rec_b,
                          float* __restrict__ out,
                          unsigned* __restrict__ flags,
                          unsigned* __restrict__ hx) {
  __shared__ __align__(16) short As_h[16 * AS_STRIDE];
  __shared__ __align__(16) short As_m[16 * AS_STRIDE];
  __shared__ __align__(16) short As_l[16 * AS_STRIDE];
  __shared__ float g_scr[4 * 16 * 17];
  __shared__ float r_scr[4 * 16 * 17];
  __shared__ float red[16][16];
  __shared__ float maskS[16];

  const int tid = threadIdx.x;
  const int bt = blockIdx.x >> 4;   // b-group (16 rows each)
  const int ht = blockIdx.x & 15;   // hh-slice (16 hh each)
  const int b0 = bt << 4, hh0 = ht << 4;
  const int w  = tid >> 6;          // wave id == gate id (f,i,o,c~)
  const int l  = tid & 63;
  const int fr = l & 15;            // MFMA frag row/col
  const int gq = l >> 4;            // MFMA k-subgroup
  const int b  = tid >> 4;          // staging/cell: local b row
  const int q  = tid & 15;          // staging slice / cell hh-local
  const int hh = hh0 + q;

  // ---- combined biases ----
  float be0 = enc_bx[0*kH+hh] + enc_bh[0*kH+hh] + enc_b[0*kH+hh];
  float be1 = enc_bx[1*kH+hh] + enc_bh[1*kH+hh] + enc_b[1*kH+hh];
  float be2 = enc_bx[2*kH+hh] + enc_bh[2*kH+hh] + enc_b[2*kH+hh];
  float be3 = enc_bx[3*kH+hh] + enc_bh[3*kH+hh] + enc_b[3*kH+hh];
  float bd0 = dec_bx[0*kH+hh] + dec_bh[0*kH+hh] + dec_b[0*kH+hh];
  float bd1 = dec_bx[1*kH+hh] + dec_bh[1*kH+hh] + dec_b[1*kH+hh];
  float bd2 = dec_bx[2*kH+hh] + dec_bh[2*kH+hh] + dec_b[2*kH+hh];
  float bd3 = dec_bx[3*kH+hh] + dec_bh[3*kH+hh] + dec_b[3*kH+hh];
  float recb = (ht < 8) ? rec_b[hh0 + q] : 0.0f;
  float creg = 0.0f;  // cell state, fp32, register-resident

  // ---- encoder weight fragments (bf16 3-way split), K=384 cat [Wx|Wh] ----
  short8 wfh[12], wfm[12], wfl[12];
#pragma unroll
  for (int kst = 0; kst < 12; ++kst) {
    int k = kst * 32 + gq * 8;
    const float* src = (k < 128)
        ? (enc_Wx + ((size_t)(w * kH) + hh0 + fr) * kI + k)
        : (enc_Wh + ((size_t)(w * kH) + hh0 + fr) * kH + (k - 128));
    short8 hi, mi, lo;
#pragma unroll
    for (int j = 0; j < 8; ++j) {
      unsigned short h_, m_, l_;
      bsplit3(src[j], h_, m_, l_);
      hi[j] = (short)h_; mi[j] = (short)m_; lo[j] = (short)l_;
    }
    wfh[kst] = hi; wfm[kst] = mi; wfl[kst] = lo;
  }

  const unsigned* flp = flags + (bt * 16 + q) * 16;  // flag of the slice this thread stages
  unsigned* flown = flags + (bt * 16 + ht) * 16;     // this block's own flag

  // ================= encoder: 512 steps =================
  for (int s = 0; s < kS; ++s) {
    const int par = s & 1;
    // stage x chunk (q<8) FIRST (independent of h -> overlaps the flag wait)
    if (q < 8) {
      const float* xp = x + ((size_t)(b0 + b) * kS + s) * kI + q * 16;
      float arr[16];
      *(float4*)(arr + 0)  = *(const float4*)(xp + 0);
      *(float4*)(arr + 4)  = *(const float4*)(xp + 4);
      *(float4*)(arr + 8)  = *(const float4*)(xp + 8);
      *(float4*)(arr + 12) = *(const float4*)(xp + 12);
      float ss = 0.f;
      short8 H0, H1, M0, M1, L0, L1;
#pragma unroll
      for (int j = 0; j < 16; ++j) {
        float v = arr[j];
        ss += v * v;
        unsigned short h_, m_, l_;
        bsplit3(v, h_, m_, l_);
        if (j < 8) { H0[j] = (short)h_; M0[j] = (short)m_; L0[j] = (short)l_; }
        else       { H1[j-8] = (short)h_; M1[j-8] = (short)m_; L1[j-8] = (short)l_; }
      }
      *(short8*)(As_h + b * AS_STRIDE + q * 16)     = H0;
      *(short8*)(As_h + b * AS_STRIDE + q * 16 + 8) = H1;
      *(short8*)(As_m + b * AS_STRIDE + q * 16)     = M0;
      *(short8*)(As_m + b * AS_STRIDE + q * 16 + 8) = M1;
      *(short8*)(As_l + b * AS_STRIDE + q * 16)     = L0;
      *(short8*)(As_l + b * AS_STRIDE + q * 16 + 8) = L1;
      red[b][q] = ss;
    }
    // stage h slice q into As[.][128+16q]: f32 -> 3-way bf16 split (exact path)
    {
      wait_flag(flp, (unsigned)s);
      size_t hxi = (((size_t)(par * 16 + bt) * 16 + b) * 256) + q * 16;
      float v[16];
#pragma unroll
      for (int i = 0; i < 16; ++i)
        v[i] = __builtin_bit_cast(float, __hip_atomic_load(hx + hxi + i, __ATOMIC_RELAXED, __HIP_MEMORY_SCOPE_SYSTEM));
      short8 H0, H1, M0, M1, L0, L1;
#pragma unroll
      for (int j = 0; j < 16; ++j) {
        unsigned short h_, m_, l_;
        bsplit3(v[j], h_, m_, l_);
        if (j < 8) { H0[j] = (short)h_; M0[j] = (short)m_; L0[j] = (short)l_; }
        else       { H1[j-8] = (short)h_; M1[j-8] = (short)m_; L1[j-8] = (short)l_; }
      }
      *(short8*)(As_h + b * AS_STRIDE + 128 + q * 16)     = H0;
      *(short8*)(As_h + b * AS_STRIDE + 128 + q * 16 + 8) = H1;
      *(short8*)(As_m + b * AS_STRIDE + 128 + q * 16)     = M0;
      *(short8*)(As_m + b * AS_STRIDE + 128 + q * 16 + 8) = M1;
      *(short8*)(As_l + b * AS_STRIDE + 128 + q * 16)     = L0;
      *(short8*)(As_l + b * AS_STRIDE + 128 + q * 16 + 8) = L1;
    }
    __syncthreads();
    if (tid < 16) {
      float ss = 0.f;
#pragma unroll
      for (int j = 0; j < 8; ++j) ss += red[tid][j];
      maskS[tid] = (ss > 1e-6f) ? 1.0f : 0.0f;
    }
    // gate GEMM: K=384, 6-term bf16 scheme (all cross terms >= 2^-27)
    f32x4 a0 = {0.f,0.f,0.f,0.f}, a1 = a0, a2 = a0, a3 = a0, a4 = a0, a5 = a0;
#pragma unroll
    for (int kst = 0; kst < 12; ++kst) {
      const short8 ah = *(const short8*)(As_h + fr * AS_STRIDE + kst * 32 + gq * 8);
      const short8 am = *(const short8*)(As_m + fr * AS_STRIDE + kst * 32 + gq * 8);
      const short8 al = *(const short8*)(As_l + fr * AS_STRIDE + kst * 32 + gq * 8);
      a0 = __builtin_amdgcn_mfma_f32_16x16x32_bf16(ah, wfh[kst], a0, 0, 0, 0);
      a1 = __builtin_amdgcn_mfma_f32_16x16x32_bf16(ah, wfm[kst], a1, 0, 0, 0);
      a2 = __builtin_amdgcn_mfma_f32_16x16x32_bf16(am, wfh[kst], a2, 0, 0, 0);
      a3 = __builtin_amdgcn_mfma_f32_16x16x32_bf16(ah, wfl[kst], a3, 0, 0, 0);
      a4 = __builtin_amdgcn_mfma_f32_16x16x32_bf16(am, wfm[kst], a4, 0, 0, 0);
      a5 = __builtin_amdgcn_mfma_f32_16x16x32_bf16(al, wfh[kst], a5, 0, 0, 0);
    }
    f32x4 d = (((a5 + a4) + a3) + (a2 + a1)) + a0;
#pragma unroll
    for (int i = 0; i < 4; ++i) g_scr[(w * 16 + gq * 4 + i) * 17 + fr] = d[i];
    __syncthreads();
    // cell update (thread owns (b, hh)); publish h as f32 bits
    {
      float gf = g_scr[(0 * 16 + b) * 17 + q] + be0;
      float gi = g_scr[(1 * 16 + b) * 17 + q] + be1;
      float go = g_scr[(2 * 16 + b) * 17 + q] + be2;
      float gc = g_scr[(3 * 16 + b) * 17 + q] + be3;
      float m  = maskS[b];
      float f_ = sigmoidf_(gf), i_ = sigmoidf_(gi), o_ = sigmoidf_(go);
      float ct = tanhf(gc);
      creg = (f_ + i_) * creg + m * (i_ * ct);
      float hval = o_ * tanhf(creg);
      size_t wi = (((size_t)(((s + 1) & 1) * 16 + bt) * 16 + b) * 256) + hh0 + q;
      __hip_atomic_store(hx + wi, __builtin_bit_cast(unsigned, hval),
                         __ATOMIC_RELAXED, __HIP_MEMORY_SCOPE_SYSTEM);
    }
    __syncthreads();
    if (tid == 0)  // RELEASE: vmcnt drain + buffer_wbl2 -> hx durable at LLC before flag
      __hip_atomic_store(flown, (unsigned)(s + 1), __ATOMIC_RELEASE, __HIP_MEMORY_SCOPE_SYSTEM);
  }

  // ---- decoder weights: wdc = dec_Wx + dec_Wh (K=256, 3-way); rec 2-way, K-split over waves ----
  short8 dwh[8], dwm[8], dwl[8];
#pragma unroll
  for (int kst = 0; kst < 8; ++kst) {
    int k = kst * 32 + gq * 8;
    const float* s1 = dec_Wx + ((size_t)(w * kH) + hh0 + fr) * kH + k;
    const float* s2 = dec_Wh + ((size_t)(w * kH) + hh0 + fr) * kH + k;
    short8 hi, mi, lo;
#pragma unroll
    for (int j = 0; j < 8; ++j) {
      unsigned short h_, m_, l_;
      bsplit3(s1[j] + s2[j], h_, m_, l_);
      hi[j] = (short)h_; mi[j] = (short)m_; lo[j] = (short)l_;
    }
    dwh[kst] = hi; dwm[kst] = mi; dwl[kst] = lo;
  }
  short8 rfh[2], rfl[2];
#pragma unroll
  for (int kk = 0; kk < 2; ++kk) {
    short8 hi = {0,0,0,0,0,0,0,0}, lo = hi;
    if (ht < 8) {
      int k = (2 * w + kk) * 32 + gq * 8;
      const float* src = rec_W + ((size_t)(hh0 + fr)) * kH + k;
#pragma unroll
      for (int j = 0; j < 8; ++j) {
        unsigned short h_, l_;
        bsplit2(src[j], h_, l_);
        hi[j] = (short)h_; lo[j] = (short)l_;
      }
    }
    rfh[kk] = hi; rfl[kk] = lo;
  }

  // ================= decoder: 512 steps =================
  for (int t = 0; t < kS; ++t) {
    const int s = kS + t;
    const int par = s & 1;
    // stage h (K=256 at offset 0), f32 -> bf16x3, mask partial exact
    {
      wait_flag(flp, (unsigned)s);
      size_t hxi = (((size_t)(par * 16 + bt) * 16 + b) * 256) + q * 16;
      float v[16];
#pragma unroll
      for (int i = 0; i < 16; ++i)
        v[i] = __builtin_bit_cast(float, __hip_atomic_load(hx + hxi + i, __ATOMIC_RELAXED, __HIP_MEMORY_SCOPE_SYSTEM));
      float ss = 0.f;
      short8 H0, H1, M0, M1, L0, L1;
#pragma unroll
      for (int j = 0; j < 16; ++j) {
        float vv = v[j];
        ss += vv * vv;
        unsigned short h_, m_, l_;
        bsplit3(vv, h_, m_, l_);
        if (j < 8) { H0[j] = (short)h_; M0[j] = (short)m_; L0[j] = (short)l_; }
        else       { H1[j-8] = (short)h_; M1[j-8] = (short)m_; L1[j-8] = (short)l_; }
      }
      *(short8*)(As_h + b * AS_STRIDE + q * 16)     = H0;
      *(short8*)(As_h + b * AS_STRIDE + q * 16 + 8) = H1;
      *(short8*)(As_m + b * AS_STRIDE + q * 16)     = M0;
      *(short8*)(As_m + b * AS_STRIDE + q * 16 + 8) = M1;
      *(short8*)(As_l + b * AS_STRIDE + q * 16)     = L0;
      *(short8*)(As_l + b * AS_STRIDE + q * 16 + 8) = L1;
      red[b][q] = ss;
    }
    __syncthreads();
    if (tid < 16) {
      float ss = 0.f;
#pragma unroll
      for (int j = 0; j < 16; ++j) ss += red[tid][j];
      maskS[tid] = (ss > 1e-6f) ? 1.0f : 0.0f;
    }
    // gate GEMM K=256, 6-term scheme
    f32x4 a0 = {0.f,0.f,0.f,0.f}, a1 = a0, a2 = a0, a3 = a0, a4 = a0, a5 = a0;
#pragma unroll
    for (int kst = 0; kst < 8; ++kst) {
      const short8 ah = *(const short8*)(As_h + fr * AS_STRIDE + kst * 32 + gq * 8);
      const short8 am = *(const short8*)(As_m + fr * AS_STRIDE + kst * 32 + gq * 8);
      const short8 al = *(const short8*)(As_l + fr * AS_STRIDE + kst * 32 + gq * 8);
      a0 = __builtin_amdgcn_mfma_f32_16x16x32_bf16(ah, dwh[kst], a0, 0, 0, 0);
      a1 = __builtin_amdgcn_mfma_f32_16x16x32_bf16(ah, dwm[kst], a1, 0, 0, 0);
      a2 = __builtin_amdgcn_mfma_f32_16x16x32_bf16(am, dwh[kst], a2, 0, 0, 0);
      a3 = __builtin_amdgcn_mfma_f32_16x16x32_bf16(ah, dwl[kst], a3, 0, 0, 0);
      a4 = __builtin_amdgcn_mfma_f32_16x16x32_bf16(am, dwm[kst], a4, 0, 0, 0);
      a5 = __builtin_amdgcn_mfma_f32_16x16x32_bf16(al, dwh[kst], a5, 0, 0, 0);
    }
    f32x4 d = (((a5 + a4) + a3) + (a2 + a1)) + a0;
#pragma unroll
    for (int i = 0; i < 4; ++i) g_scr[(w * 16 + gq * 4 + i) * 17 + fr] = d[i];
    // rec GEMM on staged h_(t-1): wave w covers ksteps {2w, 2w+1} (no amplification)
    if (ht < 8) {
      f32x4 r0 = {0.f,0.f,0.f,0.f}, r1 = r0, r2 = r0;
#pragma unroll
      for (int kk = 0; kk < 2; ++kk) {
        const short8 ah = *(const short8*)(As_h + fr * AS_STRIDE + (2 * w + kk) * 32 + gq * 8);
        const short8 am = *(const short8*)(As_m + fr * AS_STRIDE + (2 * w + kk) * 32 + gq * 8);
        r0 = __builtin_amdgcn_mfma_f32_16x16x32_bf16(ah, rfh[kk], r0, 0, 0, 0);
        r1 = __builtin_amdgcn_mfma_f32_16x16x32_bf16(ah, rfl[kk], r1, 0, 0, 0);
        r2 = __builtin_amdgcn_mfma_f32_16x16x32_bf16(am, rfh[kk], r2, 0, 0, 0);
      }
      f32x4 rd = r0 + r1 + r2;
#pragma unroll
      for (int i = 0; i < 4; ++i) r_scr[(w * 16 + gq * 4 + i) * 17 + fr] = rd[i];
    }
    __syncthreads();
    // cell update + h publish
    {
      float gf = g_scr[(0 * 16 + b) * 17 + q] + bd0;
      float gi = g_scr[(1 * 16 + b) * 17 + q] + bd1;
      float go = g_scr[(2 * 16 + b) * 17 + q] + bd2;
      float gc = g_scr[(3 * 16 + b) * 17 + q] + bd3;
      float m  = maskS[b];
      float f_ = sigmoidf_(gf), i_ = sigmoidf_(gi), o_ = sigmoidf_(go);
      float ct = tanhf(gc);
      creg = (f_ + i_) * creg + m * (i_ * ct);
      float hval = o_ * tanhf(creg);
      size_t wi = (((size_t)(((s + 1) & 1) * 16 + bt) * 16 + b) * 256) + hh0 + q;
      __hip_atomic_store(hx + wi, __builtin_bit_cast(unsigned, hval),
                         __ATOMIC_RELAXED, __HIP_MEMORY_SCOPE_SYSTEM);
    }
    // reconstruct out[:, t-1, :] from staged h_(t-1) (nontemporal: keep L2 clean)
    if (ht < 8 && t > 0) {
      float rsum = r_scr[(0 * 16 + b) * 17 + q] + r_scr[(1 * 16 + b) * 17 + q]
                 + r_scr[(2 * 16 + b) * 17 + q] + r_scr[(3 * 16 + b) * 17 + q] + recb;
      __builtin_nontemporal_store(rsum, &out[((size_t)(b0 + b) * kS + (t - 1)) * kI + hh0 + q]);
    }
    __syncthreads();
    if (tid == 0)  // RELEASE
      __hip_atomic_store(flown, (unsigned)(s + 1), __ATOMIC_RELEASE, __HIP_MEMORY_SCOPE_SYSTEM);
  }

  // ================= final rec: out[:, 511, :] from h_dec_511 =================
  {
    const int s = 2 * kS;  // 1024, parity 0
    {
      wait_flag(flp, (unsigned)s);
      size_t hxi = (((size_t)(0 * 16 + bt) * 16 + b) * 256) + q * 16;
      float v[16];
#pragma unroll
      for (int i = 0; i < 16; ++i)
        v[i] = __builtin_bit_cast(float, __hip_atomic_load(hx + hxi + i, __ATOMIC_RELAXED, __HIP_MEMORY_SCOPE_SYSTEM));
      short8 H0, H1, M0, M1;
#pragma unroll
      for (int j = 0; j < 16; ++j) {
        unsigned short h_, m_, l_;
        bsplit3(v[j], h_, m_, l_);
        if (j < 8) { H0[j] = (short)h_; M0[j] = (short)m_; }
        else       { H1[j-8] = (short)h_; M1[j-8] = (short)m_; }
      }
      *(short8*)(As_h + b * AS_STRIDE + q * 16)     = H0;
      *(short8*)(As_h + b * AS_STRIDE + q * 16 + 8) = H1;
      *(short8*)(As_m + b * AS_STRIDE + q * 16)     = M0;
      *(short8*)(As_m + b * AS_STRIDE + q * 16 + 8) = M1;
    }
    __syncthreads();
    if (ht < 8) {
      f32x4 r0 = {0.f,0.f,0.f,0.f}, r1 = r0, r2 = r0;
#pragma unroll
      for (int kk = 0; kk < 2; ++kk) {
        const short8 ah = *(const short8*)(As_h + fr * AS_STRIDE + (2 * w + kk) * 32 + gq * 8);
        const short8 am = *(const short8*)(As_m + fr * AS_STRIDE + (2 * w + kk) * 32 + gq * 8);
        r0 = __builtin_amdgcn_mfma_f32_16x16x32_bf16(ah, rfh[kk], r0, 0, 0, 0);
        r1 = __builtin_amdgcn_mfma_f32_16x16x32_bf16(ah, rfl[kk], r1, 0, 0, 0);
        r2 = __builtin_amdgcn_mfma_f32_16x16x32_bf16(am, rfh[kk], r2, 0, 0, 0);
      }
      f32x4 rd = r0 + r1 + r2;
#pragma unroll
      for (int i = 0; i < 4; ++i) r_scr[(w * 16 + gq * 4 + i) * 17 + fr] = rd[i];
    }
    __syncthreads();
    if (ht < 8) {
      float rsum = r_scr[(0 * 16 + b) * 17 + q] + r_scr[(1 * 16 + b) * 17 + q]
                 + r_scr[(2 * 16 + b) * 17 + q] + r_scr[(3 * 16 + b) * 17 + q] + recb;
      __builtin_nontemporal_store(rsum, &out[((size_t)(b0 + b) * kS + (kS - 1)) * kI + hh0 + q]);
    }
  }
}

extern "C" void kernel_launch(void* const* d_in, const int* in_sizes, int n_in,
                              void* d_out, int out_size, void* d_ws, size_t ws_size,
                              hipStream_t stream) {
  const float* x      = (const float*)d_in[0];
  const float* enc_Wx = (const float*)d_in[1];
  const float* enc_bx = (const float*)d_in[2];
  const float* enc_Wh = (const float*)d_in[3];
  const float* enc_bh = (const float*)d_in[4];
  const float* enc_b  = (const float*)d_in[5];
  const float* dec_Wx = (const float*)d_in[6];
  const float* dec_bx = (const float*)d_in[7];
  const float* dec_Wh = (const float*)d_in[8];
  const float* dec_bh = (const float*)d_in[9];
  const float* dec_b  = (const float*)d_in[10];
  const float* rec_W  = (const float*)d_in[11];
  const float* rec_b  = (const float*)d_in[12];
  float* out = (float*)d_out;

  unsigned* flags = (unsigned*)d_ws;
  unsigned* hx = (unsigned*)((char*)d_ws + WS_FLAG_BYTES);

  hipMemsetAsync(d_ws, 0, WS_FLAG_BYTES + (size_t)WS_HX_U32 * 4, stream);

  hipLaunchKernelGGL(lstm_mfma, dim3(256), dim3(256), 0, stream,
                     x, enc_Wx, enc_bx, enc_Wh, enc_bh, enc_b,
                     dec_Wx, dec_bx, dec_Wh, dec_bh, dec_b,
                     rec_W, rec_b, out, flags, hx);
}

// Round 9
// 6987.477 us; speedup vs baseline: 6.4986x; 1.3418x over previous
//
#include <hip/hip_runtime.h>
#include <cmath>

#define kB 256
#define kS 512
#define kI 128
#define kH 256

typedef __attribute__((ext_vector_type(8))) short short8;
typedef __attribute__((ext_vector_type(4))) float f32x4;
typedef unsigned long long u64;

#define AS_STRIDE 408  // bf16 elems; row stride 816B

// ws: hx u64[2 parity][16 grp][16 b][256 hh] = 1 MiB. Each element carries its
// own validity: (seq << 32) | f32bits. seq s+1 published at end of step s.
#define WS_HX_U64 (2 * 16 * 16 * 256)

__device__ __forceinline__ float sigmoidf_(float z) { return 1.0f / (1.0f + expf(-z)); }

// f32 -> bf16 RNE
__device__ __forceinline__ unsigned short f2b(float f) {
  unsigned u = __builtin_bit_cast(unsigned, f);
  unsigned r = (u + 0x7fffu + ((u >> 16) & 1u)) >> 16;
  return (unsigned short)r;
}
__device__ __forceinline__ float b2f(unsigned short s) {
  unsigned u = ((unsigned)s) << 16;
  return __builtin_bit_cast(float, u);
}
__device__ __forceinline__ void bsplit2(float f, unsigned short& h_, unsigned short& l_) {
  h_ = f2b(f);
  l_ = f2b(f - b2f(h_));
}
__device__ __forceinline__ void bsplit3(float f, unsigned short& h_, unsigned short& m_, unsigned short& l_) {
  h_ = f2b(f);
  float r1 = f - b2f(h_);
  m_ = f2b(r1);
  l_ = f2b(r1 - b2f(m_));
}

// Poll 16 contiguous seq-stamped u64 until ALL carry seq; return the f32 payloads.
// Atomicity of each 8B store makes value+validity inseparable: no fences needed.
__device__ __forceinline__ void poll16(const u64* p, unsigned seq, float* v) {
  for (;;) {
    u64 u[16];
    bool ok = true;
#pragma unroll
    for (int i = 0; i < 16; ++i)
      u[i] = __hip_atomic_load(p + i, __ATOMIC_RELAXED, __HIP_MEMORY_SCOPE_SYSTEM);
#pragma unroll
    for (int i = 0; i < 16; ++i) ok &= ((unsigned)(u[i] >> 32) == seq);
    if (ok) {
#pragma unroll
      for (int i = 0; i < 16; ++i) v[i] = __builtin_bit_cast(float, (unsigned)u[i]);
      return;
    }
    __builtin_amdgcn_s_sleep(1);
  }
}

__launch_bounds__(256, 1)
__global__ void lstm_mfma(const float* __restrict__ x,
                          const float* __restrict__ enc_Wx, const float* __restrict__ enc_bx,
                          const float* __restrict__ enc_Wh, const float* __restrict__ enc_bh,
                          const float* __restrict__ enc_b,
                          const float* __restrict__ dec_Wx, const float* __restrict__ dec_bx,
                          const float* __restrict__ dec_Wh, const float* __restrict__ dec_bh,
                          const float* __restrict__ dec_b,
                          const float* __restrict__ rec_W, const float* __restrict__ rec_b,
                          float* __restrict__ out,
                          u64* __restrict__ hx) {
  __shared__ __align__(16) short As_h[16 * AS_STRIDE];
  __shared__ __align__(16) short As_m[16 * AS_STRIDE];
  __shared__ __align__(16) short As_l[16 * AS_STRIDE];
  __shared__ float g_scr[4 * 16 * 17];
  __shared__ float r_scr[4 * 16 * 17];
  __shared__ float red[16][16];
  __shared__ float maskS[16];

  const int tid = threadIdx.x;
  const int bt = blockIdx.x >> 4;   // b-group (16 rows each)
  const int ht = blockIdx.x & 15;   // hh-slice (16 hh each)
  const int b0 = bt << 4, hh0 = ht << 4;
  const int w  = tid >> 6;          // wave id == gate id (f,i,o,c~)
  const int l  = tid & 63;
  const int fr = l & 15;            // MFMA frag row/col
  const int gq = l >> 4;            // MFMA k-subgroup
  const int b  = tid >> 4;          // staging/cell: local b row
  const int q  = tid & 15;          // staging slice / cell hh-local
  const int hh = hh0 + q;

  // ---- combined biases ----
  float be0 = enc_bx[0*kH+hh] + enc_bh[0*kH+hh] + enc_b[0*kH+hh];
  float be1 = enc_bx[1*kH+hh] + enc_bh[1*kH+hh] + enc_b[1*kH+hh];
  float be2 = enc_bx[2*kH+hh] + enc_bh[2*kH+hh] + enc_b[2*kH+hh];
  float be3 = enc_bx[3*kH+hh] + enc_bh[3*kH+hh] + enc_b[3*kH+hh];
  float bd0 = dec_bx[0*kH+hh] + dec_bh[0*kH+hh] + dec_b[0*kH+hh];
  float bd1 = dec_bx[1*kH+hh] + dec_bh[1*kH+hh] + dec_b[1*kH+hh];
  float bd2 = dec_bx[2*kH+hh] + dec_bh[2*kH+hh] + dec_b[2*kH+hh];
  float bd3 = dec_bx[3*kH+hh] + dec_bh[3*kH+hh] + dec_b[3*kH+hh];
  float recb = (ht < 8) ? rec_b[hh0 + q] : 0.0f;
  float creg = 0.0f;  // cell state, fp32, register-resident

  // ---- encoder weight fragments (bf16 3-way split), K=384 cat [Wx|Wh] ----
  short8 wfh[12], wfm[12], wfl[12];
#pragma unroll
  for (int kst = 0; kst < 12; ++kst) {
    int k = kst * 32 + gq * 8;
    const float* src = (k < 128)
        ? (enc_Wx + ((size_t)(w * kH) + hh0 + fr) * kI + k)
        : (enc_Wh + ((size_t)(w * kH) + hh0 + fr) * kH + (k - 128));
    short8 hi, mi, lo;
#pragma unroll
    for (int j = 0; j < 8; ++j) {
      unsigned short h_, m_, l_;
      bsplit3(src[j], h_, m_, l_);
      hi[j] = (short)h_; mi[j] = (short)m_; lo[j] = (short)l_;
    }
    wfh[kst] = hi; wfm[kst] = mi; wfl[kst] = lo;
  }

  // ================= encoder: 512 steps =================
  for (int s = 0; s < kS; ++s) {
    const int par = s & 1;
    // stage x chunk (q<8) FIRST (independent of h -> overlaps producer latency)
    if (q < 8) {
      const float* xp = x + ((size_t)(b0 + b) * kS + s) * kI + q * 16;
      float arr[16];
      *(float4*)(arr + 0)  = *(const float4*)(xp + 0);
      *(float4*)(arr + 4)  = *(const float4*)(xp + 4);
      *(float4*)(arr + 8)  = *(const float4*)(xp + 8);
      *(float4*)(arr + 12) = *(const float4*)(xp + 12);
      float ss = 0.f;
      short8 H0, H1, M0, M1, L0, L1;
#pragma unroll
      for (int j = 0; j < 16; ++j) {
        float v = arr[j];
        ss += v * v;
        unsigned short h_, m_, l_;
        bsplit3(v, h_, m_, l_);
        if (j < 8) { H0[j] = (short)h_; M0[j] = (short)m_; L0[j] = (short)l_; }
        else       { H1[j-8] = (short)h_; M1[j-8] = (short)m_; L1[j-8] = (short)l_; }
      }
      *(short8*)(As_h + b * AS_STRIDE + q * 16)     = H0;
      *(short8*)(As_h + b * AS_STRIDE + q * 16 + 8) = H1;
      *(short8*)(As_m + b * AS_STRIDE + q * 16)     = M0;
      *(short8*)(As_m + b * AS_STRIDE + q * 16 + 8) = M1;
      *(short8*)(As_l + b * AS_STRIDE + q * 16)     = L0;
      *(short8*)(As_l + b * AS_STRIDE + q * 16 + 8) = L1;
      red[b][q] = ss;
    }
    // stage h slice q (poll seq-stamped data directly; no flags, no fences)
    {
      const u64* ph = hx + (((size_t)(par * 16 + bt) * 16 + b) * 256) + q * 16;
      float v[16];
      poll16(ph, (unsigned)s, v);
      short8 H0, H1, M0, M1, L0, L1;
#pragma unroll
      for (int j = 0; j < 16; ++j) {
        unsigned short h_, m_, l_;
        bsplit3(v[j], h_, m_, l_);
        if (j < 8) { H0[j] = (short)h_; M0[j] = (short)m_; L0[j] = (short)l_; }
        else       { H1[j-8] = (short)h_; M1[j-8] = (short)m_; L1[j-8] = (short)l_; }
      }
      *(short8*)(As_h + b * AS_STRIDE + 128 + q * 16)     = H0;
      *(short8*)(As_h + b * AS_STRIDE + 128 + q * 16 + 8) = H1;
      *(short8*)(As_m + b * AS_STRIDE + 128 + q * 16)     = M0;
      *(short8*)(As_m + b * AS_STRIDE + 128 + q * 16 + 8) = M1;
      *(short8*)(As_l + b * AS_STRIDE + 128 + q * 16)     = L0;
      *(short8*)(As_l + b * AS_STRIDE + 128 + q * 16 + 8) = L1;
    }
    __syncthreads();  // B: staging complete
    if (tid < 16) {
      float ss = 0.f;
#pragma unroll
      for (int j = 0; j < 8; ++j) ss += red[tid][j];
      maskS[tid] = (ss > 1e-6f) ? 1.0f : 0.0f;
    }
    // gate GEMM: K=384, 6-term bf16 scheme (all cross terms >= 2^-27)
    f32x4 a0 = {0.f,0.f,0.f,0.f}, a1 = a0, a2 = a0, a3 = a0, a4 = a0, a5 = a0;
#pragma unroll
    for (int kst = 0; kst < 12; ++kst) {
      const short8 ah = *(const short8*)(As_h + fr * AS_STRIDE + kst * 32 + gq * 8);
      const short8 am = *(const short8*)(As_m + fr * AS_STRIDE + kst * 32 + gq * 8);
      const short8 al = *(const short8*)(As_l + fr * AS_STRIDE + kst * 32 + gq * 8);
      a0 = __builtin_amdgcn_mfma_f32_16x16x32_bf16(ah, wfh[kst], a0, 0, 0, 0);
      a1 = __builtin_amdgcn_mfma_f32_16x16x32_bf16(ah, wfm[kst], a1, 0, 0, 0);
      a2 = __builtin_amdgcn_mfma_f32_16x16x32_bf16(am, wfh[kst], a2, 0, 0, 0);
      a3 = __builtin_amdgcn_mfma_f32_16x16x32_bf16(ah, wfl[kst], a3, 0, 0, 0);
      a4 = __builtin_amdgcn_mfma_f32_16x16x32_bf16(am, wfm[kst], a4, 0, 0, 0);
      a5 = __builtin_amdgcn_mfma_f32_16x16x32_bf16(al, wfh[kst], a5, 0, 0, 0);
    }
    f32x4 d = (((a5 + a4) + a3) + (a2 + a1)) + a0;
#pragma unroll
    for (int i = 0; i < 4; ++i) g_scr[(w * 16 + gq * 4 + i) * 17 + fr] = d[i];
    __syncthreads();  // C
    // cell update (thread owns (b, hh)); publish h as seq-stamped u64
    {
      float gf = g_scr[(0 * 16 + b) * 17 + q] + be0;
      float gi = g_scr[(1 * 16 + b) * 17 + q] + be1;
      float go = g_scr[(2 * 16 + b) * 17 + q] + be2;
      float gc = g_scr[(3 * 16 + b) * 17 + q] + be3;
      float m  = maskS[b];
      float f_ = sigmoidf_(gf), i_ = sigmoidf_(gi), o_ = sigmoidf_(go);
      float ct = tanhf(gc);
      creg = (f_ + i_) * creg + m * (i_ * ct);
      float hval = o_ * tanhf(creg);
      u64 pk = ((u64)(unsigned)(s + 1) << 32) | (u64)__builtin_bit_cast(unsigned, hval);
      size_t wi = (((size_t)(((s + 1) & 1) * 16 + bt) * 16 + b) * 256) + hh0 + q;
      __hip_atomic_store(hx + wi, pk, __ATOMIC_RELAXED, __HIP_MEMORY_SCOPE_SYSTEM);
    }
  }

  // ---- decoder weights: wdc = dec_Wx + dec_Wh (K=256, 3-way); rec 2-way, K-split over waves ----
  short8 dwh[8], dwm[8], dwl[8];
#pragma unroll
  for (int kst = 0; kst < 8; ++kst) {
    int k = kst * 32 + gq * 8;
    const float* s1 = dec_Wx + ((size_t)(w * kH) + hh0 + fr) * kH + k;
    const float* s2 = dec_Wh + ((size_t)(w * kH) + hh0 + fr) * kH + k;
    short8 hi, mi, lo;
#pragma unroll
    for (int j = 0; j < 8; ++j) {
      unsigned short h_, m_, l_;
      bsplit3(s1[j] + s2[j], h_, m_, l_);
      hi[j] = (short)h_; mi[j] = (short)m_; lo[j] = (short)l_;
    }
    dwh[kst] = hi; dwm[kst] = mi; dwl[kst] = lo;
  }
  short8 rfh[2], rfl[2];
#pragma unroll
  for (int kk = 0; kk < 2; ++kk) {
    short8 hi = {0,0,0,0,0,0,0,0}, lo = hi;
    if (ht < 8) {
      int k = (2 * w + kk) * 32 + gq * 8;
      const float* src = rec_W + ((size_t)(hh0 + fr)) * kH + k;
#pragma unroll
      for (int j = 0; j < 8; ++j) {
        unsigned short h_, l_;
        bsplit2(src[j], h_, l_);
        hi[j] = (short)h_; lo[j] = (short)l_;
      }
    }
    rfh[kk] = hi; rfl[kk] = lo;
  }

  // ================= decoder: 512 steps =================
  for (int t = 0; t < kS; ++t) {
    const int s = kS + t;
    const int par = s & 1;
    // stage h (K=256 at offset 0), poll data, mask partial exact
    {
      const u64* ph = hx + (((size_t)(par * 16 + bt) * 16 + b) * 256) + q * 16;
      float v[16];
      poll16(ph, (unsigned)s, v);
      float ss = 0.f;
      short8 H0, H1, M0, M1, L0, L1;
#pragma unroll
      for (int j = 0; j < 16; ++j) {
        float vv = v[j];
        ss += vv * vv;
        unsigned short h_, m_, l_;
        bsplit3(vv, h_, m_, l_);
        if (j < 8) { H0[j] = (short)h_; M0[j] = (short)m_; L0[j] = (short)l_; }
        else       { H1[j-8] = (short)h_; M1[j-8] = (short)m_; L1[j-8] = (short)l_; }
      }
      *(short8*)(As_h + b * AS_STRIDE + q * 16)     = H0;
      *(short8*)(As_h + b * AS_STRIDE + q * 16 + 8) = H1;
      *(short8*)(As_m + b * AS_STRIDE + q * 16)     = M0;
      *(short8*)(As_m + b * AS_STRIDE + q * 16 + 8) = M1;
      *(short8*)(As_l + b * AS_STRIDE + q * 16)     = L0;
      *(short8*)(As_l + b * AS_STRIDE + q * 16 + 8) = L1;
      red[b][q] = ss;
    }
    __syncthreads();  // B
    if (tid < 16) {
      float ss = 0.f;
#pragma unroll
      for (int j = 0; j < 16; ++j) ss += red[tid][j];
      maskS[tid] = (ss > 1e-6f) ? 1.0f : 0.0f;
    }
    // gate GEMM K=256, 6-term scheme
    f32x4 a0 = {0.f,0.f,0.f,0.f}, a1 = a0, a2 = a0, a3 = a0, a4 = a0, a5 = a0;
#pragma unroll
    for (int kst = 0; kst < 8; ++kst) {
      const short8 ah = *(const short8*)(As_h + fr * AS_STRIDE + kst * 32 + gq * 8);
      const short8 am = *(const short8*)(As_m + fr * AS_STRIDE + kst * 32 + gq * 8);
      const short8 al = *(const short8*)(As_l + fr * AS_STRIDE + kst * 32 + gq * 8);
      a0 = __builtin_amdgcn_mfma_f32_16x16x32_bf16(ah, dwh[kst], a0, 0, 0, 0);
      a1 = __builtin_amdgcn_mfma_f32_16x16x32_bf16(ah, dwm[kst], a1, 0, 0, 0);
      a2 = __builtin_amdgcn_mfma_f32_16x16x32_bf16(am, dwh[kst], a2, 0, 0, 0);
      a3 = __builtin_amdgcn_mfma_f32_16x16x32_bf16(ah, dwl[kst], a3, 0, 0, 0);
      a4 = __builtin_amdgcn_mfma_f32_16x16x32_bf16(am, dwm[kst], a4, 0, 0, 0);
      a5 = __builtin_amdgcn_mfma_f32_16x16x32_bf16(al, dwh[kst], a5, 0, 0, 0);
    }
    f32x4 d = (((a5 + a4) + a3) + (a2 + a1)) + a0;
#pragma unroll
    for (int i = 0; i < 4; ++i) g_scr[(w * 16 + gq * 4 + i) * 17 + fr] = d[i];
    // rec GEMM on staged h_(t-1): wave w covers ksteps {2w, 2w+1} (no amplification)
    if (ht < 8) {
      f32x4 r0 = {0.f,0.f,0.f,0.f}, r1 = r0, r2 = r0;
#pragma unroll
      for (int kk = 0; kk < 2; ++kk) {
        const short8 ah = *(const short8*)(As_h + fr * AS_STRIDE + (2 * w + kk) * 32 + gq * 8);
        const short8 am = *(const short8*)(As_m + fr * AS_STRIDE + (2 * w + kk) * 32 + gq * 8);
        r0 = __builtin_amdgcn_mfma_f32_16x16x32_bf16(ah, rfh[kk], r0, 0, 0, 0);
        r1 = __builtin_amdgcn_mfma_f32_16x16x32_bf16(ah, rfl[kk], r1, 0, 0, 0);
        r2 = __builtin_amdgcn_mfma_f32_16x16x32_bf16(am, rfh[kk], r2, 0, 0, 0);
      }
      f32x4 rd = r0 + r1 + r2;
#pragma unroll
      for (int i = 0; i < 4; ++i) r_scr[(w * 16 + gq * 4 + i) * 17 + fr] = rd[i];
    }
    __syncthreads();  // C
    // cell update + seq-stamped h publish
    {
      float gf = g_scr[(0 * 16 + b) * 17 + q] + bd0;
      float gi = g_scr[(1 * 16 + b) * 17 + q] + bd1;
      float go = g_scr[(2 * 16 + b) * 17 + q] + bd2;
      float gc = g_scr[(3 * 16 + b) * 17 + q] + bd3;
      float m  = maskS[b];
      float f_ = sigmoidf_(gf), i_ = sigmoidf_(gi), o_ = sigmoidf_(go);
      float ct = tanhf(gc);
      creg = (f_ + i_) * creg + m * (i_ * ct);
      float hval = o_ * tanhf(creg);
      u64 pk = ((u64)(unsigned)(s + 1) << 32) | (u64)__builtin_bit_cast(unsigned, hval);
      size_t wi = (((size_t)(((s + 1) & 1) * 16 + bt) * 16 + b) * 256) + hh0 + q;
      __hip_atomic_store(hx + wi, pk, __ATOMIC_RELAXED, __HIP_MEMORY_SCOPE_SYSTEM);
    }
    // reconstruct out[:, t-1, :] from staged h_(t-1) (nontemporal: keep L2 clean)
    if (ht < 8 && t > 0) {
      float rsum = r_scr[(0 * 16 + b) * 17 + q] + r_scr[(1 * 16 + b) * 17 + q]
                 + r_scr[(2 * 16 + b) * 17 + q] + r_scr[(3 * 16 + b) * 17 + q] + recb;
      __builtin_nontemporal_store(rsum, &out[((size_t)(b0 + b) * kS + (t - 1)) * kI + hh0 + q]);
    }
  }

  // ================= final rec: out[:, 511, :] from h_dec_511 =================
  {
    {
      const u64* ph = hx + (((size_t)(0 * 16 + bt) * 16 + b) * 256) + q * 16;
      float v[16];
      poll16(ph, (unsigned)(2 * kS), v);
      short8 H0, H1, M0, M1;
#pragma unroll
      for (int j = 0; j < 16; ++j) {
        unsigned short h_, m_, l_;
        bsplit3(v[j], h_, m_, l_);
        if (j < 8) { H0[j] = (short)h_; M0[j] = (short)m_; }
        else       { H1[j-8] = (short)h_; M1[j-8] = (short)m_; }
      }
      *(short8*)(As_h + b * AS_STRIDE + q * 16)     = H0;
      *(short8*)(As_h + b * AS_STRIDE + q * 16 + 8) = H1;
      *(short8*)(As_m + b * AS_STRIDE + q * 16)     = M0;
      *(short8*)(As_m + b * AS_STRIDE + q * 16 + 8) = M1;
    }
    __syncthreads();
    if (ht < 8) {
      f32x4 r0 = {0.f,0.f,0.f,0.f}, r1 = r0, r2 = r0;
#pragma unroll
      for (int kk = 0; kk < 2; ++kk) {
        const short8 ah = *(const short8*)(As_h + fr * AS_STRIDE + (2 * w + kk) * 32 + gq * 8);
        const short8 am = *(const short8*)(As_m + fr * AS_STRIDE + (2 * w + kk) * 32 + gq * 8);
        r0 = __builtin_amdgcn_mfma_f32_16x16x32_bf16(ah, rfh[kk], r0, 0, 0, 0);
        r1 = __builtin_amdgcn_mfma_f32_16x16x32_bf16(ah, rfl[kk], r1, 0, 0, 0);
        r2 = __builtin_amdgcn_mfma_f32_16x16x32_bf16(am, rfh[kk], r2, 0, 0, 0);
      }
      f32x4 rd = r0 + r1 + r2;
#pragma unroll
      for (int i = 0; i < 4; ++i) r_scr[(w * 16 + gq * 4 + i) * 17 + fr] = rd[i];
    }
    __syncthreads();
    if (ht < 8) {
      float rsum = r_scr[(0 * 16 + b) * 17 + q] + r_scr[(1 * 16 + b) * 17 + q]
                 + r_scr[(2 * 16 + b) * 17 + q] + r_scr[(3 * 16 + b) * 17 + q] + recb;
      __builtin_nontemporal_store(rsum, &out[((size_t)(b0 + b) * kS + (kS - 1)) * kI + hh0 + q]);
    }
  }
}

extern "C" void kernel_launch(void* const* d_in, const int* in_sizes, int n_in,
                              void* d_out, int out_size, void* d_ws, size_t ws_size,
                              hipStream_t stream) {
  const float* x      = (const float*)d_in[0];
  const float* enc_Wx = (const float*)d_in[1];
  const float* enc_bx = (const float*)d_in[2];
  const float* enc_Wh = (const float*)d_in[3];
  const float* enc_bh = (const float*)d_in[4];
  const float* enc_b  = (const float*)d_in[5];
  const float* dec_Wx = (const float*)d_in[6];
  const float* dec_bx = (const float*)d_in[7];
  const float* dec_Wh = (const float*)d_in[8];
  const float* dec_bh = (const float*)d_in[9];
  const float* dec_b  = (const float*)d_in[10];
  const float* rec_W  = (const float*)d_in[11];
  const float* rec_b  = (const float*)d_in[12];
  float* out = (float*)d_out;

  u64* hx = (u64*)d_ws;

  // zero hx: seq=0 == "h_0 = 0 valid" for the encoder's first step
  hipMemsetAsync(d_ws, 0, (size_t)WS_HX_U64 * 8, stream);

  hipLaunchKernelGGL(lstm_mfma, dim3(256), dim3(256), 0, stream,
                     x, enc_Wx, enc_bx, enc_Wh, enc_bh, enc_b,
                     dec_Wx, dec_bx, dec_Wh, dec_bh, dec_b,
                     rec_W, rec_b, out, hx);
}

// Round 10
// 6884.428 us; speedup vs baseline: 6.5959x; 1.0150x over previous
//
#include <hip/hip_runtime.h>
#include <cmath>

#define kB 256
#define kS 512
#define kI 128
#define kH 256

typedef __attribute__((ext_vector_type(8))) short short8;
typedef __attribute__((ext_vector_type(4))) float f32x4;
typedef unsigned long long u64;

#define AS_STRIDE 408  // bf16 elems; row stride 816B

// ws: hx u64[2 parity][16 grp][16 b][256 hh] = 1 MiB. Each element carries its
// own validity: (seq << 32) | f32bits. seq s+1 published at end of step s.
#define WS_HX_U64 (2 * 16 * 16 * 256)

__device__ __forceinline__ float sigmoidf_(float z) { return 1.0f / (1.0f + expf(-z)); }

// f32 -> bf16 RNE
__device__ __forceinline__ unsigned short f2b(float f) {
  unsigned u = __builtin_bit_cast(unsigned, f);
  unsigned r = (u + 0x7fffu + ((u >> 16) & 1u)) >> 16;
  return (unsigned short)r;
}
__device__ __forceinline__ float b2f(unsigned short s) {
  unsigned u = ((unsigned)s) << 16;
  return __builtin_bit_cast(float, u);
}
__device__ __forceinline__ void bsplit2(float f, unsigned short& h_, unsigned short& l_) {
  h_ = f2b(f);
  l_ = f2b(f - b2f(h_));
}
__device__ __forceinline__ void bsplit3(float f, unsigned short& h_, unsigned short& m_, unsigned short& l_) {
  h_ = f2b(f);
  float r1 = f - b2f(h_);
  m_ = f2b(r1);
  l_ = f2b(r1 - b2f(m_));
}

// Sentinel-first poll of 16 contiguous seq-stamped u64.
// Spin cheaply on element 0 only (8B/iter, 16x less LLC traffic than full
// re-scan); the 16 elements are stored by one producer wave in the same cycle
// window, so once the sentinel lands the rest are (almost) always ready.
// Each element is still individually seq-validated -> correctness identical.
__device__ __forceinline__ void poll16(const u64* p, unsigned seq, float* v) {
  u64 u0;
  for (;;) {
    u0 = __hip_atomic_load(p, __ATOMIC_RELAXED, __HIP_MEMORY_SCOPE_SYSTEM);
    if ((unsigned)(u0 >> 32) == seq) break;
    __builtin_amdgcn_s_sleep(2);
  }
  v[0] = __builtin_bit_cast(float, (unsigned)u0);
  u64 u[16];
#pragma unroll
  for (int i = 1; i < 16; ++i)
    u[i] = __hip_atomic_load(p + i, __ATOMIC_RELAXED, __HIP_MEMORY_SCOPE_SYSTEM);
#pragma unroll
  for (int i = 1; i < 16; ++i) {
    while ((unsigned)(u[i] >> 32) != seq) {
      __builtin_amdgcn_s_sleep(1);
      u[i] = __hip_atomic_load(p + i, __ATOMIC_RELAXED, __HIP_MEMORY_SCOPE_SYSTEM);
    }
    v[i] = __builtin_bit_cast(float, (unsigned)u[i]);
  }
}

__launch_bounds__(256, 1)
__global__ void lstm_mfma(const float* __restrict__ x,
                          const float* __restrict__ enc_Wx, const float* __restrict__ enc_bx,
                          const float* __restrict__ enc_Wh, const float* __restrict__ enc_bh,
                          const float* __restrict__ enc_b,
                          const float* __restrict__ dec_Wx, const float* __restrict__ dec_bx,
                          const float* __restrict__ dec_Wh, const float* __restrict__ dec_bh,
                          const float* __restrict__ dec_b,
                          const float* __restrict__ rec_W, const float* __restrict__ rec_b,
                          float* __restrict__ out,
                          u64* __restrict__ hx) {
  __shared__ __align__(16) short As_h[16 * AS_STRIDE];
  __shared__ __align__(16) short As_m[16 * AS_STRIDE];
  __shared__ __align__(16) short As_l[16 * AS_STRIDE];
  __shared__ float g_scr[4 * 16 * 17];
  __shared__ float r_scr[4 * 16 * 17];
  __shared__ float red[16][16];
  __shared__ float maskS[16];

  const int tid = threadIdx.x;
  const int bt = blockIdx.x >> 4;   // b-group (16 rows each)
  const int ht = blockIdx.x & 15;   // hh-slice (16 hh each)
  const int b0 = bt << 4, hh0 = ht << 4;
  const int w  = tid >> 6;          // wave id == gate id (f,i,o,c~)
  const int l  = tid & 63;
  const int fr = l & 15;            // MFMA frag row/col
  const int gq = l >> 4;            // MFMA k-subgroup
  const int b  = tid >> 4;          // staging/cell: local b row
  const int q  = tid & 15;          // staging slice / cell hh-local
  const int hh = hh0 + q;

  // ---- combined biases ----
  float be0 = enc_bx[0*kH+hh] + enc_bh[0*kH+hh] + enc_b[0*kH+hh];
  float be1 = enc_bx[1*kH+hh] + enc_bh[1*kH+hh] + enc_b[1*kH+hh];
  float be2 = enc_bx[2*kH+hh] + enc_bh[2*kH+hh] + enc_b[2*kH+hh];
  float be3 = enc_bx[3*kH+hh] + enc_bh[3*kH+hh] + enc_b[3*kH+hh];
  float bd0 = dec_bx[0*kH+hh] + dec_bh[0*kH+hh] + dec_b[0*kH+hh];
  float bd1 = dec_bx[1*kH+hh] + dec_bh[1*kH+hh] + dec_b[1*kH+hh];
  float bd2 = dec_bx[2*kH+hh] + dec_bh[2*kH+hh] + dec_b[2*kH+hh];
  float bd3 = dec_bx[3*kH+hh] + dec_bh[3*kH+hh] + dec_b[3*kH+hh];
  float recb = (ht < 8) ? rec_b[hh0 + q] : 0.0f;
  float creg = 0.0f;  // cell state, fp32, register-resident

  // ---- encoder weight fragments (bf16 3-way split), K=384 cat [Wx|Wh] ----
  short8 wfh[12], wfm[12], wfl[12];
#pragma unroll
  for (int kst = 0; kst < 12; ++kst) {
    int k = kst * 32 + gq * 8;
    const float* src = (k < 128)
        ? (enc_Wx + ((size_t)(w * kH) + hh0 + fr) * kI + k)
        : (enc_Wh + ((size_t)(w * kH) + hh0 + fr) * kH + (k - 128));
    short8 hi, mi, lo;
#pragma unroll
    for (int j = 0; j < 8; ++j) {
      unsigned short h_, m_, l_;
      bsplit3(src[j], h_, m_, l_);
      hi[j] = (short)h_; mi[j] = (short)m_; lo[j] = (short)l_;
    }
    wfh[kst] = hi; wfm[kst] = mi; wfl[kst] = lo;
  }

  // ================= encoder: 512 steps =================
  for (int s = 0; s < kS; ++s) {
    const int par = s & 1;
    // stage x chunk (q<8) FIRST (independent of h -> overlaps producer latency)
    if (q < 8) {
      const float* xp = x + ((size_t)(b0 + b) * kS + s) * kI + q * 16;
      float arr[16];
      *(float4*)(arr + 0)  = *(const float4*)(xp + 0);
      *(float4*)(arr + 4)  = *(const float4*)(xp + 4);
      *(float4*)(arr + 8)  = *(const float4*)(xp + 8);
      *(float4*)(arr + 12) = *(const float4*)(xp + 12);
      float ss = 0.f;
      short8 H0, H1, M0, M1, L0, L1;
#pragma unroll
      for (int j = 0; j < 16; ++j) {
        float v = arr[j];
        ss += v * v;
        unsigned short h_, m_, l_;
        bsplit3(v, h_, m_, l_);
        if (j < 8) { H0[j] = (short)h_; M0[j] = (short)m_; L0[j] = (short)l_; }
        else       { H1[j-8] = (short)h_; M1[j-8] = (short)m_; L1[j-8] = (short)l_; }
      }
      *(short8*)(As_h + b * AS_STRIDE + q * 16)     = H0;
      *(short8*)(As_h + b * AS_STRIDE + q * 16 + 8) = H1;
      *(short8*)(As_m + b * AS_STRIDE + q * 16)     = M0;
      *(short8*)(As_m + b * AS_STRIDE + q * 16 + 8) = M1;
      *(short8*)(As_l + b * AS_STRIDE + q * 16)     = L0;
      *(short8*)(As_l + b * AS_STRIDE + q * 16 + 8) = L1;
      red[b][q] = ss;
    }
    // stage h slice q (poll seq-stamped data directly; no flags, no fences)
    {
      const u64* ph = hx + (((size_t)(par * 16 + bt) * 16 + b) * 256) + q * 16;
      float v[16];
      poll16(ph, (unsigned)s, v);
      short8 H0, H1, M0, M1, L0, L1;
#pragma unroll
      for (int j = 0; j < 16; ++j) {
        unsigned short h_, m_, l_;
        bsplit3(v[j], h_, m_, l_);
        if (j < 8) { H0[j] = (short)h_; M0[j] = (short)m_; L0[j] = (short)l_; }
        else       { H1[j-8] = (short)h_; M1[j-8] = (short)m_; L1[j-8] = (short)l_; }
      }
      *(short8*)(As_h + b * AS_STRIDE + 128 + q * 16)     = H0;
      *(short8*)(As_h + b * AS_STRIDE + 128 + q * 16 + 8) = H1;
      *(short8*)(As_m + b * AS_STRIDE + 128 + q * 16)     = M0;
      *(short8*)(As_m + b * AS_STRIDE + 128 + q * 16 + 8) = M1;
      *(short8*)(As_l + b * AS_STRIDE + 128 + q * 16)     = L0;
      *(short8*)(As_l + b * AS_STRIDE + 128 + q * 16 + 8) = L1;
    }
    __syncthreads();  // B: staging complete
    if (tid < 16) {
      float ss = 0.f;
#pragma unroll
      for (int j = 0; j < 8; ++j) ss += red[tid][j];
      maskS[tid] = (ss > 1e-6f) ? 1.0f : 0.0f;
    }
    // gate GEMM: K=384, 6-term bf16 scheme (all cross terms >= 2^-27)
    f32x4 a0 = {0.f,0.f,0.f,0.f}, a1 = a0, a2 = a0, a3 = a0, a4 = a0, a5 = a0;
#pragma unroll
    for (int kst = 0; kst < 12; ++kst) {
      const short8 ah = *(const short8*)(As_h + fr * AS_STRIDE + kst * 32 + gq * 8);
      const short8 am = *(const short8*)(As_m + fr * AS_STRIDE + kst * 32 + gq * 8);
      const short8 al = *(const short8*)(As_l + fr * AS_STRIDE + kst * 32 + gq * 8);
      a0 = __builtin_amdgcn_mfma_f32_16x16x32_bf16(ah, wfh[kst], a0, 0, 0, 0);
      a1 = __builtin_amdgcn_mfma_f32_16x16x32_bf16(ah, wfm[kst], a1, 0, 0, 0);
      a2 = __builtin_amdgcn_mfma_f32_16x16x32_bf16(am, wfh[kst], a2, 0, 0, 0);
      a3 = __builtin_amdgcn_mfma_f32_16x16x32_bf16(ah, wfl[kst], a3, 0, 0, 0);
      a4 = __builtin_amdgcn_mfma_f32_16x16x32_bf16(am, wfm[kst], a4, 0, 0, 0);
      a5 = __builtin_amdgcn_mfma_f32_16x16x32_bf16(al, wfh[kst], a5, 0, 0, 0);
    }
    f32x4 d = (((a5 + a4) + a3) + (a2 + a1)) + a0;
#pragma unroll
    for (int i = 0; i < 4; ++i) g_scr[(w * 16 + gq * 4 + i) * 17 + fr] = d[i];
    __syncthreads();  // C
    // cell update (thread owns (b, hh)); publish h as seq-stamped u64
    {
      float gf = g_scr[(0 * 16 + b) * 17 + q] + be0;
      float gi = g_scr[(1 * 16 + b) * 17 + q] + be1;
      float go = g_scr[(2 * 16 + b) * 17 + q] + be2;
      float gc = g_scr[(3 * 16 + b) * 17 + q] + be3;
      float m  = maskS[b];
      float f_ = sigmoidf_(gf), i_ = sigmoidf_(gi), o_ = sigmoidf_(go);
      float ct = tanhf(gc);
      creg = (f_ + i_) * creg + m * (i_ * ct);
      float hval = o_ * tanhf(creg);
      u64 pk = ((u64)(unsigned)(s + 1) << 32) | (u64)__builtin_bit_cast(unsigned, hval);
      size_t wi = (((size_t)(((s + 1) & 1) * 16 + bt) * 16 + b) * 256) + hh0 + q;
      __hip_atomic_store(hx + wi, pk, __ATOMIC_RELAXED, __HIP_MEMORY_SCOPE_SYSTEM);
    }
  }

  // ---- decoder weights: wdc = dec_Wx + dec_Wh (K=256, 3-way); rec 2-way, K-split over waves ----
  short8 dwh[8], dwm[8], dwl[8];
#pragma unroll
  for (int kst = 0; kst < 8; ++kst) {
    int k = kst * 32 + gq * 8;
    const float* s1 = dec_Wx + ((size_t)(w * kH) + hh0 + fr) * kH + k;
    const float* s2 = dec_Wh + ((size_t)(w * kH) + hh0 + fr) * kH + k;
    short8 hi, mi, lo;
#pragma unroll
    for (int j = 0; j < 8; ++j) {
      unsigned short h_, m_, l_;
      bsplit3(s1[j] + s2[j], h_, m_, l_);
      hi[j] = (short)h_; mi[j] = (short)m_; lo[j] = (short)l_;
    }
    dwh[kst] = hi; dwm[kst] = mi; dwl[kst] = lo;
  }
  short8 rfh[2], rfl[2];
#pragma unroll
  for (int kk = 0; kk < 2; ++kk) {
    short8 hi = {0,0,0,0,0,0,0,0}, lo = hi;
    if (ht < 8) {
      int k = (2 * w + kk) * 32 + gq * 8;
      const float* src = rec_W + ((size_t)(hh0 + fr)) * kH + k;
#pragma unroll
      for (int j = 0; j < 8; ++j) {
        unsigned short h_, l_;
        bsplit2(src[j], h_, l_);
        hi[j] = (short)h_; lo[j] = (short)l_;
      }
    }
    rfh[kk] = hi; rfl[kk] = lo;
  }

  // ================= decoder: 512 steps =================
  for (int t = 0; t < kS; ++t) {
    const int s = kS + t;
    const int par = s & 1;
    // stage h (K=256 at offset 0), poll data, mask partial exact
    {
      const u64* ph = hx + (((size_t)(par * 16 + bt) * 16 + b) * 256) + q * 16;
      float v[16];
      poll16(ph, (unsigned)s, v);
      float ss = 0.f;
      short8 H0, H1, M0, M1, L0, L1;
#pragma unroll
      for (int j = 0; j < 16; ++j) {
        float vv = v[j];
        ss += vv * vv;
        unsigned short h_, m_, l_;
        bsplit3(vv, h_, m_, l_);
        if (j < 8) { H0[j] = (short)h_; M0[j] = (short)m_; L0[j] = (short)l_; }
        else       { H1[j-8] = (short)h_; M1[j-8] = (short)m_; L1[j-8] = (short)l_; }
      }
      *(short8*)(As_h + b * AS_STRIDE + q * 16)     = H0;
      *(short8*)(As_h + b * AS_STRIDE + q * 16 + 8) = H1;
      *(short8*)(As_m + b * AS_STRIDE + q * 16)     = M0;
      *(short8*)(As_m + b * AS_STRIDE + q * 16 + 8) = M1;
      *(short8*)(As_l + b * AS_STRIDE + q * 16)     = L0;
      *(short8*)(As_l + b * AS_STRIDE + q * 16 + 8) = L1;
      red[b][q] = ss;
    }
    __syncthreads();  // B
    if (tid < 16) {
      float ss = 0.f;
#pragma unroll
      for (int j = 0; j < 16; ++j) ss += red[tid][j];
      maskS[tid] = (ss > 1e-6f) ? 1.0f : 0.0f;
    }
    // gate GEMM K=256, 6-term scheme
    f32x4 a0 = {0.f,0.f,0.f,0.f}, a1 = a0, a2 = a0, a3 = a0, a4 = a0, a5 = a0;
#pragma unroll
    for (int kst = 0; kst < 8; ++kst) {
      const short8 ah = *(const short8*)(As_h + fr * AS_STRIDE + kst * 32 + gq * 8);
      const short8 am = *(const short8*)(As_m + fr * AS_STRIDE + kst * 32 + gq * 8);
      const short8 al = *(const short8*)(As_l + fr * AS_STRIDE + kst * 32 + gq * 8);
      a0 = __builtin_amdgcn_mfma_f32_16x16x32_bf16(ah, dwh[kst], a0, 0, 0, 0);
      a1 = __builtin_amdgcn_mfma_f32_16x16x32_bf16(ah, dwm[kst], a1, 0, 0, 0);
      a2 = __builtin_amdgcn_mfma_f32_16x16x32_bf16(am, dwh[kst], a2, 0, 0, 0);
      a3 = __builtin_amdgcn_mfma_f32_16x16x32_bf16(ah, dwl[kst], a3, 0, 0, 0);
      a4 = __builtin_amdgcn_mfma_f32_16x16x32_bf16(am, dwm[kst], a4, 0, 0, 0);
      a5 = __builtin_amdgcn_mfma_f32_16x16x32_bf16(al, dwh[kst], a5, 0, 0, 0);
    }
    f32x4 d = (((a5 + a4) + a3) + (a2 + a1)) + a0;
#pragma unroll
    for (int i = 0; i < 4; ++i) g_scr[(w * 16 + gq * 4 + i) * 17 + fr] = d[i];
    // rec GEMM on staged h_(t-1): wave w covers ksteps {2w, 2w+1} (no amplification)
    if (ht < 8) {
      f32x4 r0 = {0.f,0.f,0.f,0.f}, r1 = r0, r2 = r0;
#pragma unroll
      for (int kk = 0; kk < 2; ++kk) {
        const short8 ah = *(const short8*)(As_h + fr * AS_STRIDE + (2 * w + kk) * 32 + gq * 8);
        const short8 am = *(const short8*)(As_m + fr * AS_STRIDE + (2 * w + kk) * 32 + gq * 8);
        r0 = __builtin_amdgcn_mfma_f32_16x16x32_bf16(ah, rfh[kk], r0, 0, 0, 0);
        r1 = __builtin_amdgcn_mfma_f32_16x16x32_bf16(ah, rfl[kk], r1, 0, 0, 0);
        r2 = __builtin_amdgcn_mfma_f32_16x16x32_bf16(am, rfh[kk], r2, 0, 0, 0);
      }
      f32x4 rd = r0 + r1 + r2;
#pragma unroll
      for (int i = 0; i < 4; ++i) r_scr[(w * 16 + gq * 4 + i) * 17 + fr] = rd[i];
    }
    __syncthreads();  // C
    // cell update + seq-stamped h publish
    {
      float gf = g_scr[(0 * 16 + b) * 17 + q] + bd0;
      float gi = g_scr[(1 * 16 + b) * 17 + q] + bd1;
      float go = g_scr[(2 * 16 + b) * 17 + q] + bd2;
      float gc = g_scr[(3 * 16 + b) * 17 + q] + bd3;
      float m  = maskS[b];
      float f_ = sigmoidf_(gf), i_ = sigmoidf_(gi), o_ = sigmoidf_(go);
      float ct = tanhf(gc);
      creg = (f_ + i_) * creg + m * (i_ * ct);
      float hval = o_ * tanhf(creg);
      u64 pk = ((u64)(unsigned)(s + 1) << 32) | (u64)__builtin_bit_cast(unsigned, hval);
      size_t wi = (((size_t)(((s + 1) & 1) * 16 + bt) * 16 + b) * 256) + hh0 + q;
      __hip_atomic_store(hx + wi, pk, __ATOMIC_RELAXED, __HIP_MEMORY_SCOPE_SYSTEM);
    }
    // reconstruct out[:, t-1, :] from staged h_(t-1) (nontemporal: keep L2 clean)
    if (ht < 8 && t > 0) {
      float rsum = r_scr[(0 * 16 + b) * 17 + q] + r_scr[(1 * 16 + b) * 17 + q]
                 + r_scr[(2 * 16 + b) * 17 + q] + r_scr[(3 * 16 + b) * 17 + q] + recb;
      __builtin_nontemporal_store(rsum, &out[((size_t)(b0 + b) * kS + (t - 1)) * kI + hh0 + q]);
    }
  }

  // ================= final rec: out[:, 511, :] from h_dec_511 =================
  {
    {
      const u64* ph = hx + (((size_t)(0 * 16 + bt) * 16 + b) * 256) + q * 16;
      float v[16];
      poll16(ph, (unsigned)(2 * kS), v);
      short8 H0, H1, M0, M1;
#pragma unroll
      for (int j = 0; j < 16; ++j) {
        unsigned short h_, m_, l_;
        bsplit3(v[j], h_, m_, l_);
        if (j < 8) { H0[j] = (short)h_; M0[j] = (short)m_; }
        else       { H1[j-8] = (short)h_; M1[j-8] = (short)m_; }
      }
      *(short8*)(As_h + b * AS_STRIDE + q * 16)     = H0;
      *(short8*)(As_h + b * AS_STRIDE + q * 16 + 8) = H1;
      *(short8*)(As_m + b * AS_STRIDE + q * 16)     = M0;
      *(short8*)(As_m + b * AS_STRIDE + q * 16 + 8) = M1;
    }
    __syncthreads();
    if (ht < 8) {
      f32x4 r0 = {0.f,0.f,0.f,0.f}, r1 = r0, r2 = r0;
#pragma unroll
      for (int kk = 0; kk < 2; ++kk) {
        const short8 ah = *(const short8*)(As_h + fr * AS_STRIDE + (2 * w + kk) * 32 + gq * 8);
        const short8 am = *(const short8*)(As_m + fr * AS_STRIDE + (2 * w + kk) * 32 + gq * 8);
        r0 = __builtin_amdgcn_mfma_f32_16x16x32_bf16(ah, rfh[kk], r0, 0, 0, 0);
        r1 = __builtin_amdgcn_mfma_f32_16x16x32_bf16(ah, rfl[kk], r1, 0, 0, 0);
        r2 = __builtin_amdgcn_mfma_f32_16x16x32_bf16(am, rfh[kk], r2, 0, 0, 0);
      }
      f32x4 rd = r0 + r1 + r2;
#pragma unroll
      for (int i = 0; i < 4; ++i) r_scr[(w * 16 + gq * 4 + i) * 17 + fr] = rd[i];
    }
    __syncthreads();
    if (ht < 8) {
      float rsum = r_scr[(0 * 16 + b) * 17 + q] + r_scr[(1 * 16 + b) * 17 + q]
                 + r_scr[(2 * 16 + b) * 17 + q] + r_scr[(3 * 16 + b) * 17 + q] + recb;
      __builtin_nontemporal_store(rsum, &out[((size_t)(b0 + b) * kS + (kS - 1)) * kI + hh0 + q]);
    }
  }
}

extern "C" void kernel_launch(void* const* d_in, const int* in_sizes, int n_in,
                              void* d_out, int out_size, void* d_ws, size_t ws_size,
                              hipStream_t stream) {
  const float* x      = (const float*)d_in[0];
  const float* enc_Wx = (const float*)d_in[1];
  const float* enc_bx = (const float*)d_in[2];
  const float* enc_Wh = (const float*)d_in[3];
  const float* enc_bh = (const float*)d_in[4];
  const float* enc_b  = (const float*)d_in[5];
  const float* dec_Wx = (const float*)d_in[6];
  const float* dec_bx = (const float*)d_in[7];
  const float* dec_Wh = (const float*)d_in[8];
  const float* dec_bh = (const float*)d_in[9];
  const float* dec_b  = (const float*)d_in[10];
  const float* rec_W  = (const float*)d_in[11];
  const float* rec_b  = (const float*)d_in[12];
  float* out = (float*)d_out;

  u64* hx = (u64*)d_ws;

  // zero hx: seq=0 == "h_0 = 0 valid" for the encoder's first step
  hipMemsetAsync(d_ws, 0, (size_t)WS_HX_U64 * 8, stream);

  hipLaunchKernelGGL(lstm_mfma, dim3(256), dim3(256), 0, stream,
                     x, enc_Wx, enc_bx, enc_Wh, enc_bh, enc_b,
                     dec_Wx, dec_bx, dec_Wh, dec_bh, dec_b,
                     rec_W, rec_b, out, hx);
}

// Round 11
// 5010.090 us; speedup vs baseline: 9.0635x; 1.3741x over previous
//
#include <hip/hip_runtime.h>
#include <cmath>

#define kB 256
#define kS 512
#define kI 128
#define kH 256

typedef __attribute__((ext_vector_type(8))) short short8;
typedef __attribute__((ext_vector_type(4))) float f32x4;
typedef unsigned long long u64;

#define AS_STRIDE 408  // bf16 elems; row stride 816B

// ws: hx u64[2 parity][16 grp][16 b][256 hh] = 1 MiB. Each element carries its
// own validity: (seq << 32) | f32bits. seq s+1 published at end of step s.
#define WS_HX_U64 (2 * 16 * 16 * 256)

__device__ __forceinline__ float sigmoidf_(float z) { return 1.0f / (1.0f + expf(-z)); }

// f32 -> bf16 RNE
__device__ __forceinline__ unsigned short f2b(float f) {
  unsigned u = __builtin_bit_cast(unsigned, f);
  unsigned r = (u + 0x7fffu + ((u >> 16) & 1u)) >> 16;
  return (unsigned short)r;
}
__device__ __forceinline__ float b2f(unsigned short s) {
  unsigned u = ((unsigned)s) << 16;
  return __builtin_bit_cast(float, u);
}
__device__ __forceinline__ void bsplit2(float f, unsigned short& h_, unsigned short& l_) {
  h_ = f2b(f);
  l_ = f2b(f - b2f(h_));
}
__device__ __forceinline__ void bsplit3(float f, unsigned short& h_, unsigned short& m_, unsigned short& l_) {
  h_ = f2b(f);
  float r1 = f - b2f(h_);
  m_ = f2b(r1);
  l_ = f2b(r1 - b2f(m_));
}

__launch_bounds__(256, 1)
__global__ void lstm_mfma(const float* __restrict__ x,
                          const float* __restrict__ enc_Wx, const float* __restrict__ enc_bx,
                          const float* __restrict__ enc_Wh, const float* __restrict__ enc_bh,
                          const float* __restrict__ enc_b,
                          const float* __restrict__ dec_Wx, const float* __restrict__ dec_bx,
                          const float* __restrict__ dec_Wh, const float* __restrict__ dec_bh,
                          const float* __restrict__ dec_b,
                          const float* __restrict__ rec_W, const float* __restrict__ rec_b,
                          float* __restrict__ out,
                          u64* __restrict__ hx) {
  __shared__ __align__(16) short As_h[16 * AS_STRIDE];
  __shared__ __align__(16) short As_m[16 * AS_STRIDE];
  __shared__ __align__(16) short As_l[16 * AS_STRIDE];
  __shared__ float g_scr[4 * 16 * 17];
  __shared__ float r_scr[4 * 16 * 17];
  __shared__ float red[16][16];
  __shared__ float maskS[16];

  const int tid = threadIdx.x;
  // XCD-colocating decode: blocks with the same bt are blk ≡ bt (mod 16), so
  // under round-robin dispatch a group's 16 blocks share an XCD (L2 reuse for
  // the group's shared x rows). Pure perf: protocol stays system-scope.
  const int bt = blockIdx.x & 15;   // b-group (16 rows each)
  const int ht = blockIdx.x >> 4;   // hh-slice (16 hh each)
  const int b0 = bt << 4, hh0 = ht << 4;
  const int w  = tid >> 6;          // wave id == gate id (f,i,o,c~)
  const int l  = tid & 63;
  const int fr = l & 15;            // MFMA frag row/col
  const int gq = l >> 4;            // MFMA k-subgroup
  const int b  = tid >> 4;          // cell/mask: local b row
  const int q  = tid & 15;          // cell/mask: hh-local
  const int hh = hh0 + q;

  // ---- combined biases ----
  float be0 = enc_bx[0*kH+hh] + enc_bh[0*kH+hh] + enc_b[0*kH+hh];
  float be1 = enc_bx[1*kH+hh] + enc_bh[1*kH+hh] + enc_b[1*kH+hh];
  float be2 = enc_bx[2*kH+hh] + enc_bh[2*kH+hh] + enc_b[2*kH+hh];
  float be3 = enc_bx[3*kH+hh] + enc_bh[3*kH+hh] + enc_b[3*kH+hh];
  float bd0 = dec_bx[0*kH+hh] + dec_bh[0*kH+hh] + dec_b[0*kH+hh];
  float bd1 = dec_bx[1*kH+hh] + dec_bh[1*kH+hh] + dec_b[1*kH+hh];
  float bd2 = dec_bx[2*kH+hh] + dec_bh[2*kH+hh] + dec_b[2*kH+hh];
  float bd3 = dec_bx[3*kH+hh] + dec_bh[3*kH+hh] + dec_b[3*kH+hh];
  float recb = (ht < 8) ? rec_b[hh0 + q] : 0.0f;
  float creg = 0.0f;  // cell state, fp32, register-resident

  // ---- encoder weight fragments (bf16 3-way split), K=384 cat [Wx|Wh] ----
  short8 wfh[12], wfm[12], wfl[12];
#pragma unroll
  for (int kst = 0; kst < 12; ++kst) {
    int k = kst * 32 + gq * 8;
    const float* src = (k < 128)
        ? (enc_Wx + ((size_t)(w * kH) + hh0 + fr) * kI + k)
        : (enc_Wh + ((size_t)(w * kH) + hh0 + fr) * kH + (k - 128));
    short8 hi, mi, lo;
#pragma unroll
    for (int j = 0; j < 8; ++j) {
      unsigned short h_, m_, l_;
      bsplit3(src[j], h_, m_, l_);
      hi[j] = (short)h_; mi[j] = (short)m_; lo[j] = (short)l_;
    }
    wfh[kst] = hi; wfm[kst] = mi; wfl[kst] = lo;
  }

  // ================= encoder: 512 steps =================
  for (int s = 0; s < kS; ++s) {
    const int par = s & 1;
    // stage x chunk (q<8) FIRST (independent of h -> overlaps producer latency)
    if (q < 8) {
      const float* xp = x + ((size_t)(b0 + b) * kS + s) * kI + q * 16;
      float arr[16];
      *(float4*)(arr + 0)  = *(const float4*)(xp + 0);
      *(float4*)(arr + 4)  = *(const float4*)(xp + 4);
      *(float4*)(arr + 8)  = *(const float4*)(xp + 8);
      *(float4*)(arr + 12) = *(const float4*)(xp + 12);
      float ss = 0.f;
      short8 H0, H1, M0, M1, L0, L1;
#pragma unroll
      for (int j = 0; j < 16; ++j) {
        float v = arr[j];
        ss += v * v;
        unsigned short h_, m_, l_;
        bsplit3(v, h_, m_, l_);
        if (j < 8) { H0[j] = (short)h_; M0[j] = (short)m_; L0[j] = (short)l_; }
        else       { H1[j-8] = (short)h_; M1[j-8] = (short)m_; L1[j-8] = (short)l_; }
      }
      *(short8*)(As_h + b * AS_STRIDE + q * 16)     = H0;
      *(short8*)(As_h + b * AS_STRIDE + q * 16 + 8) = H1;
      *(short8*)(As_m + b * AS_STRIDE + q * 16)     = M0;
      *(short8*)(As_m + b * AS_STRIDE + q * 16 + 8) = M1;
      *(short8*)(As_l + b * AS_STRIDE + q * 16)     = L0;
      *(short8*)(As_l + b * AS_STRIDE + q * 16 + 8) = L1;
      red[b][q] = ss;
    }
    // stage h: COALESCED transposed read. Thread tid reads element tid of each
    // of the 16 rows -> per instruction 64 lanes hit 64 consecutive u64 (512B,
    // one transaction) instead of a 64-line gather. Self-validating per element.
    {
      const u64* grp = hx + ((size_t)(par * 16 + bt) * 16) * 256;
      u64 u[16];
#pragma unroll
      for (int j = 0; j < 16; ++j)
        u[j] = __hip_atomic_load(grp + (size_t)j * 256 + tid, __ATOMIC_RELAXED, __HIP_MEMORY_SCOPE_SYSTEM);
#pragma unroll
      for (int j = 0; j < 16; ++j) {
        while ((unsigned)(u[j] >> 32) != (unsigned)s) {
          __builtin_amdgcn_s_sleep(1);
          u[j] = __hip_atomic_load(grp + (size_t)j * 256 + tid, __ATOMIC_RELAXED, __HIP_MEMORY_SCOPE_SYSTEM);
        }
        float v = __builtin_bit_cast(float, (unsigned)u[j]);
        unsigned short h_, m_, l_;
        bsplit3(v, h_, m_, l_);
        As_h[j * AS_STRIDE + 128 + tid] = (short)h_;   // lane-consecutive b16 writes: conflict-free
        As_m[j * AS_STRIDE + 128 + tid] = (short)m_;
        As_l[j * AS_STRIDE + 128 + tid] = (short)l_;
      }
    }
    __syncthreads();  // B: staging complete
    if (tid < 16) {
      float ss = 0.f;
#pragma unroll
      for (int j = 0; j < 8; ++j) ss += red[tid][j];
      maskS[tid] = (ss > 1e-6f) ? 1.0f : 0.0f;
    }
    // gate GEMM: K=384, 6-term bf16 scheme (all cross terms >= 2^-27)
    f32x4 a0 = {0.f,0.f,0.f,0.f}, a1 = a0, a2 = a0, a3 = a0, a4 = a0, a5 = a0;
#pragma unroll
    for (int kst = 0; kst < 12; ++kst) {
      const short8 ah = *(const short8*)(As_h + fr * AS_STRIDE + kst * 32 + gq * 8);
      const short8 am = *(const short8*)(As_m + fr * AS_STRIDE + kst * 32 + gq * 8);
      const short8 al = *(const short8*)(As_l + fr * AS_STRIDE + kst * 32 + gq * 8);
      a0 = __builtin_amdgcn_mfma_f32_16x16x32_bf16(ah, wfh[kst], a0, 0, 0, 0);
      a1 = __builtin_amdgcn_mfma_f32_16x16x32_bf16(ah, wfm[kst], a1, 0, 0, 0);
      a2 = __builtin_amdgcn_mfma_f32_16x16x32_bf16(am, wfh[kst], a2, 0, 0, 0);
      a3 = __builtin_amdgcn_mfma_f32_16x16x32_bf16(ah, wfl[kst], a3, 0, 0, 0);
      a4 = __builtin_amdgcn_mfma_f32_16x16x32_bf16(am, wfm[kst], a4, 0, 0, 0);
      a5 = __builtin_amdgcn_mfma_f32_16x16x32_bf16(al, wfh[kst], a5, 0, 0, 0);
    }
    f32x4 d = (((a5 + a4) + a3) + (a2 + a1)) + a0;
#pragma unroll
    for (int i = 0; i < 4; ++i) g_scr[(w * 16 + gq * 4 + i) * 17 + fr] = d[i];
    __syncthreads();  // C
    // cell update (thread owns (b, hh)); publish h as seq-stamped u64
    {
      float gf = g_scr[(0 * 16 + b) * 17 + q] + be0;
      float gi = g_scr[(1 * 16 + b) * 17 + q] + be1;
      float go = g_scr[(2 * 16 + b) * 17 + q] + be2;
      float gc = g_scr[(3 * 16 + b) * 17 + q] + be3;
      float m  = maskS[b];
      float f_ = sigmoidf_(gf), i_ = sigmoidf_(gi), o_ = sigmoidf_(go);
      float ct = tanhf(gc);
      creg = (f_ + i_) * creg + m * (i_ * ct);
      float hval = o_ * tanhf(creg);
      u64 pk = ((u64)(unsigned)(s + 1) << 32) | (u64)__builtin_bit_cast(unsigned, hval);
      size_t wi = (((size_t)(((s + 1) & 1) * 16 + bt) * 16 + b) * 256) + hh0 + q;
      __hip_atomic_store(hx + wi, pk, __ATOMIC_RELAXED, __HIP_MEMORY_SCOPE_SYSTEM);
    }
  }

  // ---- decoder weights: wdc = dec_Wx + dec_Wh (K=256, 3-way); rec 2-way, K-split over waves ----
  short8 dwh[8], dwm[8], dwl[8];
#pragma unroll
  for (int kst = 0; kst < 8; ++kst) {
    int k = kst * 32 + gq * 8;
    const float* s1 = dec_Wx + ((size_t)(w * kH) + hh0 + fr) * kH + k;
    const float* s2 = dec_Wh + ((size_t)(w * kH) + hh0 + fr) * kH + k;
    short8 hi, mi, lo;
#pragma unroll
    for (int j = 0; j < 8; ++j) {
      unsigned short h_, m_, l_;
      bsplit3(s1[j] + s2[j], h_, m_, l_);
      hi[j] = (short)h_; mi[j] = (short)m_; lo[j] = (short)l_;
    }
    dwh[kst] = hi; dwm[kst] = mi; dwl[kst] = lo;
  }
  short8 rfh[2], rfl[2];
#pragma unroll
  for (int kk = 0; kk < 2; ++kk) {
    short8 hi = {0,0,0,0,0,0,0,0}, lo = hi;
    if (ht < 8) {
      int k = (2 * w + kk) * 32 + gq * 8;
      const float* src = rec_W + ((size_t)(hh0 + fr)) * kH + k;
#pragma unroll
      for (int j = 0; j < 8; ++j) {
        unsigned short h_, l_;
        bsplit2(src[j], h_, l_);
        hi[j] = (short)h_; lo[j] = (short)l_;
      }
    }
    rfh[kk] = hi; rfl[kk] = lo;
  }

  // ================= decoder: 512 steps =================
  for (int t = 0; t < kS; ++t) {
    const int s = kS + t;
    const int par = s & 1;
    // stage h coalesced (colbase 0)
    {
      const u64* grp = hx + ((size_t)(par * 16 + bt) * 16) * 256;
      u64 u[16];
#pragma unroll
      for (int j = 0; j < 16; ++j)
        u[j] = __hip_atomic_load(grp + (size_t)j * 256 + tid, __ATOMIC_RELAXED, __HIP_MEMORY_SCOPE_SYSTEM);
#pragma unroll
      for (int j = 0; j < 16; ++j) {
        while ((unsigned)(u[j] >> 32) != (unsigned)s) {
          __builtin_amdgcn_s_sleep(1);
          u[j] = __hip_atomic_load(grp + (size_t)j * 256 + tid, __ATOMIC_RELAXED, __HIP_MEMORY_SCOPE_SYSTEM);
        }
        float v = __builtin_bit_cast(float, (unsigned)u[j]);
        unsigned short h_, m_, l_;
        bsplit3(v, h_, m_, l_);
        As_h[j * AS_STRIDE + tid] = (short)h_;
        As_m[j * AS_STRIDE + tid] = (short)m_;
        As_l[j * AS_STRIDE + tid] = (short)l_;
      }
    }
    __syncthreads();  // B1: As complete
    // silence-mask partials from exact LDS reconstruction (h==hi+mid+lo)
    {
      float ss = 0.f;
#pragma unroll
      for (int g2 = 0; g2 < 2; ++g2) {
        const short8 hv = *(const short8*)(As_h + b * AS_STRIDE + q * 16 + g2 * 8);
        const short8 mv = *(const short8*)(As_m + b * AS_STRIDE + q * 16 + g2 * 8);
        const short8 lv = *(const short8*)(As_l + b * AS_STRIDE + q * 16 + g2 * 8);
#pragma unroll
        for (int j = 0; j < 8; ++j) {
          float v = b2f((unsigned short)hv[j]) + b2f((unsigned short)mv[j]) + b2f((unsigned short)lv[j]);
          ss += v * v;
        }
      }
      red[b][q] = ss;
    }
    __syncthreads();  // B2: red complete
    if (tid < 16) {
      float ss = 0.f;
#pragma unroll
      for (int j = 0; j < 16; ++j) ss += red[tid][j];
      maskS[tid] = (ss > 1e-6f) ? 1.0f : 0.0f;
    }
    // gate GEMM K=256, 6-term scheme
    f32x4 a0 = {0.f,0.f,0.f,0.f}, a1 = a0, a2 = a0, a3 = a0, a4 = a0, a5 = a0;
#pragma unroll
    for (int kst = 0; kst < 8; ++kst) {
      const short8 ah = *(const short8*)(As_h + fr * AS_STRIDE + kst * 32 + gq * 8);
      const short8 am = *(const short8*)(As_m + fr * AS_STRIDE + kst * 32 + gq * 8);
      const short8 al = *(const short8*)(As_l + fr * AS_STRIDE + kst * 32 + gq * 8);
      a0 = __builtin_amdgcn_mfma_f32_16x16x32_bf16(ah, dwh[kst], a0, 0, 0, 0);
      a1 = __builtin_amdgcn_mfma_f32_16x16x32_bf16(ah, dwm[kst], a1, 0, 0, 0);
      a2 = __builtin_amdgcn_mfma_f32_16x16x32_bf16(am, dwh[kst], a2, 0, 0, 0);
      a3 = __builtin_amdgcn_mfma_f32_16x16x32_bf16(ah, dwl[kst], a3, 0, 0, 0);
      a4 = __builtin_amdgcn_mfma_f32_16x16x32_bf16(am, dwm[kst], a4, 0, 0, 0);
      a5 = __builtin_amdgcn_mfma_f32_16x16x32_bf16(al, dwh[kst], a5, 0, 0, 0);
    }
    f32x4 d = (((a5 + a4) + a3) + (a2 + a1)) + a0;
#pragma unroll
    for (int i = 0; i < 4; ++i) g_scr[(w * 16 + gq * 4 + i) * 17 + fr] = d[i];
    // rec GEMM on staged h_(t-1): wave w covers ksteps {2w, 2w+1} (no amplification)
    if (ht < 8) {
      f32x4 r0 = {0.f,0.f,0.f,0.f}, r1 = r0, r2 = r0;
#pragma unroll
      for (int kk = 0; kk < 2; ++kk) {
        const short8 ah = *(const short8*)(As_h + fr * AS_STRIDE + (2 * w + kk) * 32 + gq * 8);
        const short8 am = *(const short8*)(As_m + fr * AS_STRIDE + (2 * w + kk) * 32 + gq * 8);
        r0 = __builtin_amdgcn_mfma_f32_16x16x32_bf16(ah, rfh[kk], r0, 0, 0, 0);
        r1 = __builtin_amdgcn_mfma_f32_16x16x32_bf16(ah, rfl[kk], r1, 0, 0, 0);
        r2 = __builtin_amdgcn_mfma_f32_16x16x32_bf16(am, rfh[kk], r2, 0, 0, 0);
      }
      f32x4 rd = r0 + r1 + r2;
#pragma unroll
      for (int i = 0; i < 4; ++i) r_scr[(w * 16 + gq * 4 + i) * 17 + fr] = rd[i];
    }
    __syncthreads();  // C
    // cell update + seq-stamped h publish
    {
      float gf = g_scr[(0 * 16 + b) * 17 + q] + bd0;
      float gi = g_scr[(1 * 16 + b) * 17 + q] + bd1;
      float go = g_scr[(2 * 16 + b) * 17 + q] + bd2;
      float gc = g_scr[(3 * 16 + b) * 17 + q] + bd3;
      float m  = maskS[b];
      float f_ = sigmoidf_(gf), i_ = sigmoidf_(gi), o_ = sigmoidf_(go);
      float ct = tanhf(gc);
      creg = (f_ + i_) * creg + m * (i_ * ct);
      float hval = o_ * tanhf(creg);
      u64 pk = ((u64)(unsigned)(s + 1) << 32) | (u64)__builtin_bit_cast(unsigned, hval);
      size_t wi = (((size_t)(((s + 1) & 1) * 16 + bt) * 16 + b) * 256) + hh0 + q;
      __hip_atomic_store(hx + wi, pk, __ATOMIC_RELAXED, __HIP_MEMORY_SCOPE_SYSTEM);
    }
    // reconstruct out[:, t-1, :] from staged h_(t-1) (nontemporal: keep L2 clean)
    if (ht < 8 && t > 0) {
      float rsum = r_scr[(0 * 16 + b) * 17 + q] + r_scr[(1 * 16 + b) * 17 + q]
                 + r_scr[(2 * 16 + b) * 17 + q] + r_scr[(3 * 16 + b) * 17 + q] + recb;
      __builtin_nontemporal_store(rsum, &out[((size_t)(b0 + b) * kS + (t - 1)) * kI + hh0 + q]);
    }
  }

  // ================= final rec: out[:, 511, :] from h_dec_511 =================
  {
    {
      const u64* grp = hx + ((size_t)(0 * 16 + bt) * 16) * 256;
      u64 u[16];
#pragma unroll
      for (int j = 0; j < 16; ++j)
        u[j] = __hip_atomic_load(grp + (size_t)j * 256 + tid, __ATOMIC_RELAXED, __HIP_MEMORY_SCOPE_SYSTEM);
#pragma unroll
      for (int j = 0; j < 16; ++j) {
        while ((unsigned)(u[j] >> 32) != (unsigned)(2 * kS)) {
          __builtin_amdgcn_s_sleep(1);
          u[j] = __hip_atomic_load(grp + (size_t)j * 256 + tid, __ATOMIC_RELAXED, __HIP_MEMORY_SCOPE_SYSTEM);
        }
        float v = __builtin_bit_cast(float, (unsigned)u[j]);
        unsigned short h_, m_, l_;
        bsplit3(v, h_, m_, l_);
        As_h[j * AS_STRIDE + tid] = (short)h_;
        As_m[j * AS_STRIDE + tid] = (short)m_;
      }
    }
    __syncthreads();
    if (ht < 8) {
      f32x4 r0 = {0.f,0.f,0.f,0.f}, r1 = r0, r2 = r0;
#pragma unroll
      for (int kk = 0; kk < 2; ++kk) {
        const short8 ah = *(const short8*)(As_h + fr * AS_STRIDE + (2 * w + kk) * 32 + gq * 8);
        const short8 am = *(const short8*)(As_m + fr * AS_STRIDE + (2 * w + kk) * 32 + gq * 8);
        r0 = __builtin_amdgcn_mfma_f32_16x16x32_bf16(ah, rfh[kk], r0, 0, 0, 0);
        r1 = __builtin_amdgcn_mfma_f32_16x16x32_bf16(ah, rfl[kk], r1, 0, 0, 0);
        r2 = __builtin_amdgcn_mfma_f32_16x16x32_bf16(am, rfh[kk], r2, 0, 0, 0);
      }
      f32x4 rd = r0 + r1 + r2;
#pragma unroll
      for (int i = 0; i < 4; ++i) r_scr[(w * 16 + gq * 4 + i) * 17 + fr] = rd[i];
    }
    __syncthreads();
    if (ht < 8) {
      float rsum = r_scr[(0 * 16 + b) * 17 + q] + r_scr[(1 * 16 + b) * 17 + q]
                 + r_scr[(2 * 16 + b) * 17 + q] + r_scr[(3 * 16 + b) * 17 + q] + recb;
      __builtin_nontemporal_store(rsum, &out[((size_t)(b0 + b) * kS + (kS - 1)) * kI + hh0 + q]);
    }
  }
}

extern "C" void kernel_launch(void* const* d_in, const int* in_sizes, int n_in,
                              void* d_out, int out_size, void* d_ws, size_t ws_size,
                              hipStream_t stream) {
  const float* x      = (const float*)d_in[0];
  const float* enc_Wx = (const float*)d_in[1];
  const float* enc_bx = (const float*)d_in[2];
  const float* enc_Wh = (const float*)d_in[3];
  const float* enc_bh = (const float*)d_in[4];
  const float* enc_b  = (const float*)d_in[5];
  const float* dec_Wx = (const float*)d_in[6];
  const float* dec_bx = (const float*)d_in[7];
  const float* dec_Wh = (const float*)d_in[8];
  const float* dec_bh = (const float*)d_in[9];
  const float* dec_b  = (const float*)d_in[10];
  const float* rec_W  = (const float*)d_in[11];
  const float* rec_b  = (const float*)d_in[12];
  float* out = (float*)d_out;

  u64* hx = (u64*)d_ws;

  // zero hx: seq=0 == "h_0 = 0 valid" for the encoder's first step
  hipMemsetAsync(d_ws, 0, (size_t)WS_HX_U64 * 8, stream);

  hipLaunchKernelGGL(lstm_mfma, dim3(256), dim3(256), 0, stream,
                     x, enc_Wx, enc_bx, enc_Wh, enc_bh, enc_b,
                     dec_Wx, dec_bx, dec_Wh, dec_bh, dec_b,
                     rec_W, rec_b, out, hx);
}

// Round 12
// 3935.194 us; speedup vs baseline: 11.5392x; 1.2731x over previous
//
#include <hip/hip_runtime.h>
#include <cmath>

#define kB 256
#define kS 512
#define kI 128
#define kH 256

typedef __attribute__((ext_vector_type(8))) short short8;
typedef __attribute__((ext_vector_type(4))) float f32x4;
typedef unsigned long long u64;

#define AS_STRIDE 408  // bf16 elems; row stride 816B

// ws: hx u64[2 parity][16 grp][16 b][256 hh] = 1 MiB. Each element carries its
// own validity AND the producer-computed 3-way bf16 split:
//   u64 = (seq16 << 48) | (hi << 32) | (mid << 16) | lo
// seq16 = (s+1) & 0xffff published at end of step s (max seq 1025 << 2^16, and
// the parity double-buffer bounds slot reuse to +-2 steps -> no aliasing).
#define WS_HX_U64 (2 * 16 * 16 * 256)

__device__ __forceinline__ float sigmoidf_(float z) { return 1.0f / (1.0f + expf(-z)); }

// f32 -> bf16 RNE
__device__ __forceinline__ unsigned short f2b(float f) {
  unsigned u = __builtin_bit_cast(unsigned, f);
  unsigned r = (u + 0x7fffu + ((u >> 16) & 1u)) >> 16;
  return (unsigned short)r;
}
__device__ __forceinline__ float b2f(unsigned short s) {
  unsigned u = ((unsigned)s) << 16;
  return __builtin_bit_cast(float, u);
}
__device__ __forceinline__ void bsplit2(float f, unsigned short& h_, unsigned short& l_) {
  h_ = f2b(f);
  l_ = f2b(f - b2f(h_));
}
__device__ __forceinline__ void bsplit3(float f, unsigned short& h_, unsigned short& m_, unsigned short& l_) {
  h_ = f2b(f);
  float r1 = f - b2f(h_);
  m_ = f2b(r1);
  l_ = f2b(r1 - b2f(m_));
}

// Coalesced transposed poll: thread tid reads element tid of each of the 16
// rows (64 lanes x consecutive u64 = one 512B transaction per instruction).
// Batched retry: re-load ALL missing elements per sweep (overlapped latency)
// instead of serial per-element spins -> a straggler producer costs ~1 LLC
// round trip, not 16.
__device__ __forceinline__ void pollrow(const u64* grp, int tid, unsigned seq16, u64* u) {
  unsigned miss = 0xffffu;
  for (;;) {
    unsigned nm = 0;
#pragma unroll
    for (int j = 0; j < 16; ++j)
      if (miss & (1u << j))
        u[j] = __hip_atomic_load(grp + (size_t)j * 256 + tid, __ATOMIC_RELAXED, __HIP_MEMORY_SCOPE_SYSTEM);
#pragma unroll
    for (int j = 0; j < 16; ++j)
      if ((miss & (1u << j)) && (unsigned)(u[j] >> 48) != seq16) nm |= 1u << j;
    if (!nm) return;
    miss = nm;
    __builtin_amdgcn_s_sleep(1);
  }
}

__launch_bounds__(256, 1)
__global__ void lstm_mfma(const float* __restrict__ x,
                          const float* __restrict__ enc_Wx, const float* __restrict__ enc_bx,
                          const float* __restrict__ enc_Wh, const float* __restrict__ enc_bh,
                          const float* __restrict__ enc_b,
                          const float* __restrict__ dec_Wx, const float* __restrict__ dec_bx,
                          const float* __restrict__ dec_Wh, const float* __restrict__ dec_bh,
                          const float* __restrict__ dec_b,
                          const float* __restrict__ rec_W, const float* __restrict__ rec_b,
                          float* __restrict__ out,
                          u64* __restrict__ hx) {
  __shared__ __align__(16) short As_h[16 * AS_STRIDE];
  __shared__ __align__(16) short As_m[16 * AS_STRIDE];
  __shared__ __align__(16) short As_l[16 * AS_STRIDE];
  __shared__ float g_scr[4 * 16 * 17];
  __shared__ float r_scr[4 * 16 * 17];
  __shared__ float red[16][16];
  __shared__ float maskS[16];

  const int tid = threadIdx.x;
  // XCD-colocating decode: a group's 16 blocks are blk ≡ bt (mod 16) -> same
  // XCD under round-robin dispatch (L2 reuse). Pure perf; protocol stays
  // system-scope so correctness never depends on placement.
  const int bt = blockIdx.x & 15;   // b-group (16 rows each)
  const int ht = blockIdx.x >> 4;   // hh-slice (16 hh each)
  const int b0 = bt << 4, hh0 = ht << 4;
  const int w  = tid >> 6;          // wave id == gate id (f,i,o,c~)
  const int l  = tid & 63;
  const int fr = l & 15;            // MFMA frag row/col
  const int gq = l >> 4;            // MFMA k-subgroup
  const int b  = tid >> 4;          // cell/mask: local b row
  const int q  = tid & 15;          // cell/mask: hh-local
  const int hh = hh0 + q;

  // ---- combined biases ----
  float be0 = enc_bx[0*kH+hh] + enc_bh[0*kH+hh] + enc_b[0*kH+hh];
  float be1 = enc_bx[1*kH+hh] + enc_bh[1*kH+hh] + enc_b[1*kH+hh];
  float be2 = enc_bx[2*kH+hh] + enc_bh[2*kH+hh] + enc_b[2*kH+hh];
  float be3 = enc_bx[3*kH+hh] + enc_bh[3*kH+hh] + enc_b[3*kH+hh];
  float bd0 = dec_bx[0*kH+hh] + dec_bh[0*kH+hh] + dec_b[0*kH+hh];
  float bd1 = dec_bx[1*kH+hh] + dec_bh[1*kH+hh] + dec_b[1*kH+hh];
  float bd2 = dec_bx[2*kH+hh] + dec_bh[2*kH+hh] + dec_b[2*kH+hh];
  float bd3 = dec_bx[3*kH+hh] + dec_bh[3*kH+hh] + dec_b[3*kH+hh];
  float recb = (ht < 8) ? rec_b[hh0 + q] : 0.0f;
  float creg = 0.0f;  // cell state, fp32, register-resident

  // ---- encoder weight fragments (bf16 3-way split), K=384 cat [Wx|Wh] ----
  short8 wfh[12], wfm[12], wfl[12];
#pragma unroll
  for (int kst = 0; kst < 12; ++kst) {
    int k = kst * 32 + gq * 8;
    const float* src = (k < 128)
        ? (enc_Wx + ((size_t)(w * kH) + hh0 + fr) * kI + k)
        : (enc_Wh + ((size_t)(w * kH) + hh0 + fr) * kH + (k - 128));
    short8 hi, mi, lo;
#pragma unroll
    for (int j = 0; j < 8; ++j) {
      unsigned short h_, m_, l_;
      bsplit3(src[j], h_, m_, l_);
      hi[j] = (short)h_; mi[j] = (short)m_; lo[j] = (short)l_;
    }
    wfh[kst] = hi; wfm[kst] = mi; wfl[kst] = lo;
  }

  // ================= encoder: 512 steps =================
  for (int s = 0; s < kS; ++s) {
    const int par = s & 1;
    // stage x chunk (q<8) FIRST (independent of h -> overlaps producer latency)
    if (q < 8) {
      const float* xp = x + ((size_t)(b0 + b) * kS + s) * kI + q * 16;
      float arr[16];
      *(float4*)(arr + 0)  = *(const float4*)(xp + 0);
      *(float4*)(arr + 4)  = *(const float4*)(xp + 4);
      *(float4*)(arr + 8)  = *(const float4*)(xp + 8);
      *(float4*)(arr + 12) = *(const float4*)(xp + 12);
      float ss = 0.f;
      short8 H0, H1, M0, M1, L0, L1;
#pragma unroll
      for (int j = 0; j < 16; ++j) {
        float v = arr[j];
        ss += v * v;
        unsigned short h_, m_, l_;
        bsplit3(v, h_, m_, l_);
        if (j < 8) { H0[j] = (short)h_; M0[j] = (short)m_; L0[j] = (short)l_; }
        else       { H1[j-8] = (short)h_; M1[j-8] = (short)m_; L1[j-8] = (short)l_; }
      }
      *(short8*)(As_h + b * AS_STRIDE + q * 16)     = H0;
      *(short8*)(As_h + b * AS_STRIDE + q * 16 + 8) = H1;
      *(short8*)(As_m + b * AS_STRIDE + q * 16)     = M0;
      *(short8*)(As_m + b * AS_STRIDE + q * 16 + 8) = M1;
      *(short8*)(As_l + b * AS_STRIDE + q * 16)     = L0;
      *(short8*)(As_l + b * AS_STRIDE + q * 16 + 8) = L1;
      red[b][q] = ss;
    }
    // stage h: coalesced poll of producer-packed splits, unpack = 3 shifts
    {
      const u64* grp = hx + ((size_t)(par * 16 + bt) * 16) * 256;
      u64 u[16];
      pollrow(grp, tid, (unsigned)(s & 0xffff), u);
#pragma unroll
      for (int j = 0; j < 16; ++j) {
        As_h[j * AS_STRIDE + 128 + tid] = (short)(unsigned short)(u[j] >> 32);
        As_m[j * AS_STRIDE + 128 + tid] = (short)(unsigned short)(u[j] >> 16);
        As_l[j * AS_STRIDE + 128 + tid] = (short)(unsigned short)(u[j]);
      }
    }
    __syncthreads();  // B: staging complete
    if (tid < 16) {
      float ss = 0.f;
#pragma unroll
      for (int j = 0; j < 8; ++j) ss += red[tid][j];
      maskS[tid] = (ss > 1e-6f) ? 1.0f : 0.0f;
    }
    // gate GEMM: K=384, 6-term bf16 scheme (all cross terms >= 2^-27)
    f32x4 a0 = {0.f,0.f,0.f,0.f}, a1 = a0, a2 = a0, a3 = a0, a4 = a0, a5 = a0;
#pragma unroll
    for (int kst = 0; kst < 12; ++kst) {
      const short8 ah = *(const short8*)(As_h + fr * AS_STRIDE + kst * 32 + gq * 8);
      const short8 am = *(const short8*)(As_m + fr * AS_STRIDE + kst * 32 + gq * 8);
      const short8 al = *(const short8*)(As_l + fr * AS_STRIDE + kst * 32 + gq * 8);
      a0 = __builtin_amdgcn_mfma_f32_16x16x32_bf16(ah, wfh[kst], a0, 0, 0, 0);
      a1 = __builtin_amdgcn_mfma_f32_16x16x32_bf16(ah, wfm[kst], a1, 0, 0, 0);
      a2 = __builtin_amdgcn_mfma_f32_16x16x32_bf16(am, wfh[kst], a2, 0, 0, 0);
      a3 = __builtin_amdgcn_mfma_f32_16x16x32_bf16(ah, wfl[kst], a3, 0, 0, 0);
      a4 = __builtin_amdgcn_mfma_f32_16x16x32_bf16(am, wfm[kst], a4, 0, 0, 0);
      a5 = __builtin_amdgcn_mfma_f32_16x16x32_bf16(al, wfh[kst], a5, 0, 0, 0);
    }
    f32x4 d = (((a5 + a4) + a3) + (a2 + a1)) + a0;
#pragma unroll
    for (int i = 0; i < 4; ++i) g_scr[(w * 16 + gq * 4 + i) * 17 + fr] = d[i];
    __syncthreads();  // C
    // cell update (thread owns (b, hh)); producer splits h ONCE and publishes
    {
      float gf = g_scr[(0 * 16 + b) * 17 + q] + be0;
      float gi = g_scr[(1 * 16 + b) * 17 + q] + be1;
      float go = g_scr[(2 * 16 + b) * 17 + q] + be2;
      float gc = g_scr[(3 * 16 + b) * 17 + q] + be3;
      float m  = maskS[b];
      float f_ = sigmoidf_(gf), i_ = sigmoidf_(gi), o_ = sigmoidf_(go);
      float ct = tanhf(gc);
      creg = (f_ + i_) * creg + m * (i_ * ct);
      float hval = o_ * tanhf(creg);
      unsigned short hb, mb2, lb;
      bsplit3(hval, hb, mb2, lb);
      u64 pk = ((u64)(unsigned)((s + 1) & 0xffff) << 48) | ((u64)hb << 32) | ((u64)mb2 << 16) | (u64)lb;
      size_t wi = (((size_t)(((s + 1) & 1) * 16 + bt) * 16 + b) * 256) + hh0 + q;
      __hip_atomic_store(hx + wi, pk, __ATOMIC_RELAXED, __HIP_MEMORY_SCOPE_SYSTEM);
    }
  }

  // ---- decoder weights: wdc = dec_Wx + dec_Wh (K=256, 3-way); rec 2-way, K-split over waves ----
  short8 dwh[8], dwm[8], dwl[8];
#pragma unroll
  for (int kst = 0; kst < 8; ++kst) {
    int k = kst * 32 + gq * 8;
    const float* s1 = dec_Wx + ((size_t)(w * kH) + hh0 + fr) * kH + k;
    const float* s2 = dec_Wh + ((size_t)(w * kH) + hh0 + fr) * kH + k;
    short8 hi, mi, lo;
#pragma unroll
    for (int j = 0; j < 8; ++j) {
      unsigned short h_, m_, l_;
      bsplit3(s1[j] + s2[j], h_, m_, l_);
      hi[j] = (short)h_; mi[j] = (short)m_; lo[j] = (short)l_;
    }
    dwh[kst] = hi; dwm[kst] = mi; dwl[kst] = lo;
  }
  short8 rfh[2], rfl[2];
#pragma unroll
  for (int kk = 0; kk < 2; ++kk) {
    short8 hi = {0,0,0,0,0,0,0,0}, lo = hi;
    if (ht < 8) {
      int k = (2 * w + kk) * 32 + gq * 8;
      const float* src = rec_W + ((size_t)(hh0 + fr)) * kH + k;
#pragma unroll
      for (int j = 0; j < 8; ++j) {
        unsigned short h_, l_;
        bsplit2(src[j], h_, l_);
        hi[j] = (short)h_; lo[j] = (short)l_;
      }
    }
    rfh[kk] = hi; rfl[kk] = lo;
  }

  // ================= decoder: 512 steps =================
  for (int t = 0; t < kS; ++t) {
    const int s = kS + t;
    const int par = s & 1;
    // stage h coalesced (colbase 0), packed splits
    {
      const u64* grp = hx + ((size_t)(par * 16 + bt) * 16) * 256;
      u64 u[16];
      pollrow(grp, tid, (unsigned)(s & 0xffff), u);
#pragma unroll
      for (int j = 0; j < 16; ++j) {
        As_h[j * AS_STRIDE + tid] = (short)(unsigned short)(u[j] >> 32);
        As_m[j * AS_STRIDE + tid] = (short)(unsigned short)(u[j] >> 16);
        As_l[j * AS_STRIDE + tid] = (short)(unsigned short)(u[j]);
      }
    }
    __syncthreads();  // B1: As complete
    // silence-mask partials from LDS reconstruction (h ~= hi+mid+lo, err 2^-26)
    {
      float ss = 0.f;
#pragma unroll
      for (int g2 = 0; g2 < 2; ++g2) {
        const short8 hv = *(const short8*)(As_h + b * AS_STRIDE + q * 16 + g2 * 8);
        const short8 mv = *(const short8*)(As_m + b * AS_STRIDE + q * 16 + g2 * 8);
        const short8 lv = *(const short8*)(As_l + b * AS_STRIDE + q * 16 + g2 * 8);
#pragma unroll
        for (int j = 0; j < 8; ++j) {
          float v = b2f((unsigned short)hv[j]) + b2f((unsigned short)mv[j]) + b2f((unsigned short)lv[j]);
          ss += v * v;
        }
      }
      red[b][q] = ss;
    }
    __syncthreads();  // B2: red complete
    if (tid < 16) {
      float ss = 0.f;
#pragma unroll
      for (int j = 0; j < 16; ++j) ss += red[tid][j];
      maskS[tid] = (ss > 1e-6f) ? 1.0f : 0.0f;
    }
    // gate GEMM K=256, 6-term scheme
    f32x4 a0 = {0.f,0.f,0.f,0.f}, a1 = a0, a2 = a0, a3 = a0, a4 = a0, a5 = a0;
#pragma unroll
    for (int kst = 0; kst < 8; ++kst) {
      const short8 ah = *(const short8*)(As_h + fr * AS_STRIDE + kst * 32 + gq * 8);
      const short8 am = *(const short8*)(As_m + fr * AS_STRIDE + kst * 32 + gq * 8);
      const short8 al = *(const short8*)(As_l + fr * AS_STRIDE + kst * 32 + gq * 8);
      a0 = __builtin_amdgcn_mfma_f32_16x16x32_bf16(ah, dwh[kst], a0, 0, 0, 0);
      a1 = __builtin_amdgcn_mfma_f32_16x16x32_bf16(ah, dwm[kst], a1, 0, 0, 0);
      a2 = __builtin_amdgcn_mfma_f32_16x16x32_bf16(am, dwh[kst], a2, 0, 0, 0);
      a3 = __builtin_amdgcn_mfma_f32_16x16x32_bf16(ah, dwl[kst], a3, 0, 0, 0);
      a4 = __builtin_amdgcn_mfma_f32_16x16x32_bf16(am, dwm[kst], a4, 0, 0, 0);
      a5 = __builtin_amdgcn_mfma_f32_16x16x32_bf16(al, dwh[kst], a5, 0, 0, 0);
    }
    f32x4 d = (((a5 + a4) + a3) + (a2 + a1)) + a0;
#pragma unroll
    for (int i = 0; i < 4; ++i) g_scr[(w * 16 + gq * 4 + i) * 17 + fr] = d[i];
    // rec GEMM on staged h_(t-1): wave w covers ksteps {2w, 2w+1} (no amplification)
    if (ht < 8) {
      f32x4 r0 = {0.f,0.f,0.f,0.f}, r1 = r0, r2 = r0;
#pragma unroll
      for (int kk = 0; kk < 2; ++kk) {
        const short8 ah = *(const short8*)(As_h + fr * AS_STRIDE + (2 * w + kk) * 32 + gq * 8);
        const short8 am = *(const short8*)(As_m + fr * AS_STRIDE + (2 * w + kk) * 32 + gq * 8);
        r0 = __builtin_amdgcn_mfma_f32_16x16x32_bf16(ah, rfh[kk], r0, 0, 0, 0);
        r1 = __builtin_amdgcn_mfma_f32_16x16x32_bf16(ah, rfl[kk], r1, 0, 0, 0);
        r2 = __builtin_amdgcn_mfma_f32_16x16x32_bf16(am, rfh[kk], r2, 0, 0, 0);
      }
      f32x4 rd = r0 + r1 + r2;
#pragma unroll
      for (int i = 0; i < 4; ++i) r_scr[(w * 16 + gq * 4 + i) * 17 + fr] = rd[i];
    }
    __syncthreads();  // C
    // cell update + packed-split publish
    {
      float gf = g_scr[(0 * 16 + b) * 17 + q] + bd0;
      float gi = g_scr[(1 * 16 + b) * 17 + q] + bd1;
      float go = g_scr[(2 * 16 + b) * 17 + q] + bd2;
      float gc = g_scr[(3 * 16 + b) * 17 + q] + bd3;
      float m  = maskS[b];
      float f_ = sigmoidf_(gf), i_ = sigmoidf_(gi), o_ = sigmoidf_(go);
      float ct = tanhf(gc);
      creg = (f_ + i_) * creg + m * (i_ * ct);
      float hval = o_ * tanhf(creg);
      unsigned short hb, mb2, lb;
      bsplit3(hval, hb, mb2, lb);
      u64 pk = ((u64)(unsigned)((s + 1) & 0xffff) << 48) | ((u64)hb << 32) | ((u64)mb2 << 16) | (u64)lb;
      size_t wi = (((size_t)(((s + 1) & 1) * 16 + bt) * 16 + b) * 256) + hh0 + q;
      __hip_atomic_store(hx + wi, pk, __ATOMIC_RELAXED, __HIP_MEMORY_SCOPE_SYSTEM);
    }
    // reconstruct out[:, t-1, :] from staged h_(t-1) (nontemporal: keep L2 clean)
    if (ht < 8 && t > 0) {
      float rsum = r_scr[(0 * 16 + b) * 17 + q] + r_scr[(1 * 16 + b) * 17 + q]
                 + r_scr[(2 * 16 + b) * 17 + q] + r_scr[(3 * 16 + b) * 17 + q] + recb;
      __builtin_nontemporal_store(rsum, &out[((size_t)(b0 + b) * kS + (t - 1)) * kI + hh0 + q]);
    }
  }

  // ================= final rec: out[:, 511, :] from h_dec_511 =================
  {
    {
      const u64* grp = hx + ((size_t)(0 * 16 + bt) * 16) * 256;
      u64 u[16];
      pollrow(grp, tid, (unsigned)((2 * kS) & 0xffff), u);
#pragma unroll
      for (int j = 0; j < 16; ++j) {
        As_h[j * AS_STRIDE + tid] = (short)(unsigned short)(u[j] >> 32);
        As_m[j * AS_STRIDE + tid] = (short)(unsigned short)(u[j] >> 16);
      }
    }
    __syncthreads();
    if (ht < 8) {
      f32x4 r0 = {0.f,0.f,0.f,0.f}, r1 = r0, r2 = r0;
#pragma unroll
      for (int kk = 0; kk < 2; ++kk) {
        const short8 ah = *(const short8*)(As_h + fr * AS_STRIDE + (2 * w + kk) * 32 + gq * 8);
        const short8 am = *(const short8*)(As_m + fr * AS_STRIDE + (2 * w + kk) * 32 + gq * 8);
        r0 = __builtin_amdgcn_mfma_f32_16x16x32_bf16(ah, rfh[kk], r0, 0, 0, 0);
        r1 = __builtin_amdgcn_mfma_f32_16x16x32_bf16(ah, rfl[kk], r1, 0, 0, 0);
        r2 = __builtin_amdgcn_mfma_f32_16x16x32_bf16(am, rfh[kk], r2, 0, 0, 0);
      }
      f32x4 rd = r0 + r1 + r2;
#pragma unroll
      for (int i = 0; i < 4; ++i) r_scr[(w * 16 + gq * 4 + i) * 17 + fr] = rd[i];
    }
    __syncthreads();
    if (ht < 8) {
      float rsum = r_scr[(0 * 16 + b) * 17 + q] + r_scr[(1 * 16 + b) * 17 + q]
                 + r_scr[(2 * 16 + b) * 17 + q] + r_scr[(3 * 16 + b) * 17 + q] + recb;
      __builtin_nontemporal_store(rsum, &out[((size_t)(b0 + b) * kS + (kS - 1)) * kI + hh0 + q]);
    }
  }
}

extern "C" void kernel_launch(void* const* d_in, const int* in_sizes, int n_in,
                              void* d_out, int out_size, void* d_ws, size_t ws_size,
                              hipStream_t stream) {
  const float* x      = (const float*)d_in[0];
  const float* enc_Wx = (const float*)d_in[1];
  const float* enc_bx = (const float*)d_in[2];
  const float* enc_Wh = (const float*)d_in[3];
  const float* enc_bh = (const float*)d_in[4];
  const float* enc_b  = (const float*)d_in[5];
  const float* dec_Wx = (const float*)d_in[6];
  const float* dec_bx = (const float*)d_in[7];
  const float* dec_Wh = (const float*)d_in[8];
  const float* dec_bh = (const float*)d_in[9];
  const float* dec_b  = (const float*)d_in[10];
  const float* rec_W  = (const float*)d_in[11];
  const float* rec_b  = (const float*)d_in[12];
  float* out = (float*)d_out;

  u64* hx = (u64*)d_ws;

  // zero hx: seq=0 with zero payload == "h_0 = 0 valid" for the first step
  hipMemsetAsync(d_ws, 0, (size_t)WS_HX_U64 * 8, stream);

  hipLaunchKernelGGL(lstm_mfma, dim3(256), dim3(256), 0, stream,
                     x, enc_Wx, enc_bx, enc_Wh, enc_bh, enc_b,
                     dec_Wx, dec_bx, dec_Wh, dec_bh, dec_b,
                     rec_W, rec_b, out, hx);
}

// Round 13
// 3754.368 us; speedup vs baseline: 12.0950x; 1.0482x over previous
//
#include <hip/hip_runtime.h>
#include <cmath>

#define kB 256
#define kS 512
#define kI 128
#define kH 256

typedef __attribute__((ext_vector_type(8))) short short8;
typedef __attribute__((ext_vector_type(4))) float f32x4;
typedef unsigned long long u64;

#define AS_STRIDE 408  // bf16 elems; row stride 816B

// ws: hx u64[2 parity][16 grp][16 b][256 hh] = 1 MiB. Each element carries its
// own validity AND the producer-computed 3-way bf16 split:
//   u64 = (seq16 << 48) | (hi << 32) | (mid << 16) | lo
#define WS_HX_U64 (2 * 16 * 16 * 256)

__device__ __forceinline__ float sigmoidf_(float z) { return 1.0f / (1.0f + expf(-z)); }

// f32 -> bf16 RNE
__device__ __forceinline__ unsigned short f2b(float f) {
  unsigned u = __builtin_bit_cast(unsigned, f);
  unsigned r = (u + 0x7fffu + ((u >> 16) & 1u)) >> 16;
  return (unsigned short)r;
}
__device__ __forceinline__ float b2f(unsigned short s) {
  unsigned u = ((unsigned)s) << 16;
  return __builtin_bit_cast(float, u);
}
__device__ __forceinline__ void bsplit2(float f, unsigned short& h_, unsigned short& l_) {
  h_ = f2b(f);
  l_ = f2b(f - b2f(h_));
}
__device__ __forceinline__ void bsplit3(float f, unsigned short& h_, unsigned short& m_, unsigned short& l_) {
  h_ = f2b(f);
  float r1 = f - b2f(h_);
  m_ = f2b(r1);
  l_ = f2b(r1 - b2f(m_));
}

// Coalesced transposed poll of 8 rows at one column; batched stale-retry.
__device__ __forceinline__ void pollrow8(const u64* grp, int col, int rbase,
                                         unsigned seq16, u64* u) {
  unsigned miss = 0xffu;
  for (;;) {
    unsigned nm = 0;
#pragma unroll
    for (int j = 0; j < 8; ++j)
      if (miss & (1u << j))
        u[j] = __hip_atomic_load(grp + (size_t)(rbase + j) * 256 + col,
                                 __ATOMIC_RELAXED, __HIP_MEMORY_SCOPE_SYSTEM);
#pragma unroll
    for (int j = 0; j < 8; ++j)
      if ((miss & (1u << j)) && (unsigned)(u[j] >> 48) != seq16) nm |= 1u << j;
    if (!nm) return;
    miss = nm;
    __builtin_amdgcn_s_sleep(1);
  }
}

// 8-wave block: waves 0..7 = (gate w&3, hh-subtile w>>2). Block owns 32 hh for
// 16 b rows; group = 8 blocks (one per 32-hh slice) -> straggler domain 8.
__launch_bounds__(512, 2)
__global__ void lstm_mfma(const float* __restrict__ x,
                          const float* __restrict__ enc_Wx, const float* __restrict__ enc_bx,
                          const float* __restrict__ enc_Wh, const float* __restrict__ enc_bh,
                          const float* __restrict__ enc_b,
                          const float* __restrict__ dec_Wx, const float* __restrict__ dec_bx,
                          const float* __restrict__ dec_Wh, const float* __restrict__ dec_bh,
                          const float* __restrict__ dec_b,
                          const float* __restrict__ rec_W, const float* __restrict__ rec_b,
                          float* __restrict__ out,
                          u64* __restrict__ hx) {
  __shared__ __align__(16) short As_h[16 * AS_STRIDE];
  __shared__ __align__(16) short As_m[16 * AS_STRIDE];
  __shared__ __align__(16) short As_l[16 * AS_STRIDE];
  __shared__ float g_scr[8 * 16 * 17];
  __shared__ float r_scr[8 * 16 * 17];
  __shared__ float red[16][16];
  __shared__ float maskS[16];

  const int tid = threadIdx.x;
  // XCD-colocating decode: group bt = blocks ≡ bt (mod 16) -> same XCD under
  // round-robin (16 ≡ 0 mod 8). Pure perf; protocol stays system-scope.
  const int bt = blockIdx.x & 15;   // b-group (16 rows each)
  const int ht = blockIdx.x >> 4;   // hh-slice (0..7, 32 hh each)
  const int b0 = bt << 4, hh0 = ht << 5;
  const int w  = tid >> 6;          // wave 0..7: gate w&3, hh-subtile w>>2
  const int l  = tid & 63;
  const int fr = l & 15;            // MFMA frag row/col
  const int gq = l >> 4;            // MFMA k-subgroup
  const int cb = tid >> 5;          // cell: local b row (0..15)
  const int cq = tid & 31;          // cell: hh-local (0..31)
  const int hhc = hh0 + cq;
  const int col  = tid & 255;       // staging: column
  const int rbase = (tid >> 8) * 8; // staging: 8-row half

  // ---- combined biases (per cell thread) ----
  float be0 = enc_bx[0*kH+hhc] + enc_bh[0*kH+hhc] + enc_b[0*kH+hhc];
  float be1 = enc_bx[1*kH+hhc] + enc_bh[1*kH+hhc] + enc_b[1*kH+hhc];
  float be2 = enc_bx[2*kH+hhc] + enc_bh[2*kH+hhc] + enc_b[2*kH+hhc];
  float be3 = enc_bx[3*kH+hhc] + enc_bh[3*kH+hhc] + enc_b[3*kH+hhc];
  float bd0 = dec_bx[0*kH+hhc] + dec_bh[0*kH+hhc] + dec_b[0*kH+hhc];
  float bd1 = dec_bx[1*kH+hhc] + dec_bh[1*kH+hhc] + dec_b[1*kH+hhc];
  float bd2 = dec_bx[2*kH+hhc] + dec_bh[2*kH+hhc] + dec_b[2*kH+hhc];
  float bd3 = dec_bx[3*kH+hhc] + dec_bh[3*kH+hhc] + dec_b[3*kH+hhc];
  float recb = (ht < 4) ? rec_b[ht * 32 + cq] : 0.0f;
  float creg = 0.0f;  // cell state, fp32, register-resident

  // ---- encoder weight fragments (bf16 3-way split), K=384 cat [Wx|Wh] ----
  const int g  = w & 3;                       // gate
  const int hw = hh0 + ((w >> 2) << 4) + fr;  // weight row (hh)
  short8 wfh[12], wfm[12], wfl[12];
#pragma unroll
  for (int kst = 0; kst < 12; ++kst) {
    int k = kst * 32 + gq * 8;
    const float* src = (k < 128)
        ? (enc_Wx + ((size_t)(g * kH) + hw) * kI + k)
        : (enc_Wh + ((size_t)(g * kH) + hw) * kH + (k - 128));
    short8 hi, mi, lo;
#pragma unroll
    for (int j = 0; j < 8; ++j) {
      unsigned short h_, m_, l_;
      bsplit3(src[j], h_, m_, l_);
      hi[j] = (short)h_; mi[j] = (short)m_; lo[j] = (short)l_;
    }
    wfh[kst] = hi; wfm[kst] = mi; wfl[kst] = lo;
  }

  // ================= encoder: 512 steps =================
  for (int s = 0; s < kS; ++s) {
    const int par = s & 1;
    // stage x (tid<256, q<8): 128 threads, 16 values each
    if (tid < 256 && (tid & 15) < 8) {
      const int xb = tid >> 4, xq = tid & 15;
      const float* xp = x + ((size_t)(b0 + xb) * kS + s) * kI + xq * 16;
      float arr[16];
      *(float4*)(arr + 0)  = *(const float4*)(xp + 0);
      *(float4*)(arr + 4)  = *(const float4*)(xp + 4);
      *(float4*)(arr + 8)  = *(const float4*)(xp + 8);
      *(float4*)(arr + 12) = *(const float4*)(xp + 12);
      float ss = 0.f;
      short8 H0, H1, M0, M1, L0, L1;
#pragma unroll
      for (int j = 0; j < 16; ++j) {
        float v = arr[j];
        ss += v * v;
        unsigned short h_, m_, l_;
        bsplit3(v, h_, m_, l_);
        if (j < 8) { H0[j] = (short)h_; M0[j] = (short)m_; L0[j] = (short)l_; }
        else       { H1[j-8] = (short)h_; M1[j-8] = (short)m_; L1[j-8] = (short)l_; }
      }
      *(short8*)(As_h + xb * AS_STRIDE + xq * 16)     = H0;
      *(short8*)(As_h + xb * AS_STRIDE + xq * 16 + 8) = H1;
      *(short8*)(As_m + xb * AS_STRIDE + xq * 16)     = M0;
      *(short8*)(As_m + xb * AS_STRIDE + xq * 16 + 8) = M1;
      *(short8*)(As_l + xb * AS_STRIDE + xq * 16)     = L0;
      *(short8*)(As_l + xb * AS_STRIDE + xq * 16 + 8) = L1;
      red[xb][xq] = ss;
    }
    // stage h: coalesced poll of producer-packed splits (8 rows per thread)
    {
      const u64* grp = hx + ((size_t)(par * 16 + bt) * 16) * 256;
      u64 u[8];
      pollrow8(grp, col, rbase, (unsigned)(s & 0xffff), u);
#pragma unroll
      for (int j = 0; j < 8; ++j) {
        As_h[(rbase + j) * AS_STRIDE + 128 + col] = (short)(unsigned short)(u[j] >> 32);
        As_m[(rbase + j) * AS_STRIDE + 128 + col] = (short)(unsigned short)(u[j] >> 16);
        As_l[(rbase + j) * AS_STRIDE + 128 + col] = (short)(unsigned short)(u[j]);
      }
    }
    __syncthreads();  // B
    if (tid < 16) {
      float ss = 0.f;
#pragma unroll
      for (int j = 0; j < 8; ++j) ss += red[tid][j];
      maskS[tid] = (ss > 1e-6f) ? 1.0f : 0.0f;
    }
    // gate GEMM: K=384, 6-term bf16 scheme
    f32x4 a0 = {0.f,0.f,0.f,0.f}, a1 = a0, a2 = a0, a3 = a0, a4 = a0, a5 = a0;
#pragma unroll
    for (int kst = 0; kst < 12; ++kst) {
      const short8 ah = *(const short8*)(As_h + fr * AS_STRIDE + kst * 32 + gq * 8);
      const short8 am = *(const short8*)(As_m + fr * AS_STRIDE + kst * 32 + gq * 8);
      const short8 al = *(const short8*)(As_l + fr * AS_STRIDE + kst * 32 + gq * 8);
      a0 = __builtin_amdgcn_mfma_f32_16x16x32_bf16(ah, wfh[kst], a0, 0, 0, 0);
      a1 = __builtin_amdgcn_mfma_f32_16x16x32_bf16(ah, wfm[kst], a1, 0, 0, 0);
      a2 = __builtin_amdgcn_mfma_f32_16x16x32_bf16(am, wfh[kst], a2, 0, 0, 0);
      a3 = __builtin_amdgcn_mfma_f32_16x16x32_bf16(ah, wfl[kst], a3, 0, 0, 0);
      a4 = __builtin_amdgcn_mfma_f32_16x16x32_bf16(am, wfm[kst], a4, 0, 0, 0);
      a5 = __builtin_amdgcn_mfma_f32_16x16x32_bf16(al, wfh[kst], a5, 0, 0, 0);
    }
    f32x4 d = (((a5 + a4) + a3) + (a2 + a1)) + a0;
#pragma unroll
    for (int i = 0; i < 4; ++i) g_scr[(w * 16 + gq * 4 + i) * 17 + fr] = d[i];
    __syncthreads();  // C
    // cell update (thread owns (cb, hhc)); producer splits once and publishes
    {
      const int hsub = (cq >> 4) * 4, fq = cq & 15;
      float gf = g_scr[((0 + hsub) * 16 + cb) * 17 + fq] + be0;
      float gi = g_scr[((1 + hsub) * 16 + cb) * 17 + fq] + be1;
      float go = g_scr[((2 + hsub) * 16 + cb) * 17 + fq] + be2;
      float gc = g_scr[((3 + hsub) * 16 + cb) * 17 + fq] + be3;
      float m  = maskS[cb];
      float f_ = sigmoidf_(gf), i_ = sigmoidf_(gi), o_ = sigmoidf_(go);
      float ct = tanhf(gc);
      creg = (f_ + i_) * creg + m * (i_ * ct);
      float hval = o_ * tanhf(creg);
      unsigned short hb, mb2, lb;
      bsplit3(hval, hb, mb2, lb);
      u64 pk = ((u64)(unsigned)((s + 1) & 0xffff) << 48) | ((u64)hb << 32) | ((u64)mb2 << 16) | (u64)lb;
      size_t wi = (((size_t)(((s + 1) & 1) * 16 + bt) * 16 + cb) * 256) + hhc;
      __hip_atomic_store(hx + wi, pk, __ATOMIC_RELAXED, __HIP_MEMORY_SCOPE_SYSTEM);
    }
  }

  // ---- decoder weights: wdc = dec_Wx + dec_Wh (K=256, 3-way) ----
  short8 dwh[8], dwm[8], dwl[8];
#pragma unroll
  for (int kst = 0; kst < 8; ++kst) {
    int k = kst * 32 + gq * 8;
    const float* s1 = dec_Wx + ((size_t)(g * kH) + hw) * kH + k;
    const float* s2 = dec_Wh + ((size_t)(g * kH) + hw) * kH + k;
    short8 hi, mi, lo;
#pragma unroll
    for (int j = 0; j < 8; ++j) {
      unsigned short h_, m_, l_;
      bsplit3(s1[j] + s2[j], h_, m_, l_);
      hi[j] = (short)h_; mi[j] = (short)m_; lo[j] = (short)l_;
    }
    dwh[kst] = hi; dwm[kst] = mi; dwl[kst] = lo;
  }
  // rec weights (ht<4): wave w -> col-subtile w>>2, kstep pair {2*(w&3), 2*(w&3)+1}
  short8 rfh[2], rfl[2];
#pragma unroll
  for (int kk = 0; kk < 2; ++kk) {
    short8 hi = {0,0,0,0,0,0,0,0}, lo = hi;
    if (ht < 4) {
      int k = (2 * (w & 3) + kk) * 32 + gq * 8;
      const float* src = rec_W + ((size_t)(ht * 32 + ((w >> 2) << 4) + fr)) * kH + k;
#pragma unroll
      for (int j = 0; j < 8; ++j) {
        unsigned short h_, l_;
        bsplit2(src[j], h_, l_);
        hi[j] = (short)h_; lo[j] = (short)l_;
      }
    }
    rfh[kk] = hi; rfl[kk] = lo;
  }

  // ================= decoder: 512 steps =================
  for (int t = 0; t < kS; ++t) {
    const int s = kS + t;
    const int par = s & 1;
    // stage h coalesced (col offset 0)
    {
      const u64* grp = hx + ((size_t)(par * 16 + bt) * 16) * 256;
      u64 u[8];
      pollrow8(grp, col, rbase, (unsigned)(s & 0xffff), u);
#pragma unroll
      for (int j = 0; j < 8; ++j) {
        As_h[(rbase + j) * AS_STRIDE + col] = (short)(unsigned short)(u[j] >> 32);
        As_m[(rbase + j) * AS_STRIDE + col] = (short)(unsigned short)(u[j] >> 16);
        As_l[(rbase + j) * AS_STRIDE + col] = (short)(unsigned short)(u[j]);
      }
    }
    __syncthreads();  // B1: As complete
    // silence-mask partials from LDS reconstruction
    if (tid < 256) {
      const int mb = tid >> 4, mq = tid & 15;
      float ss = 0.f;
#pragma unroll
      for (int g2 = 0; g2 < 2; ++g2) {
        const short8 hv = *(const short8*)(As_h + mb * AS_STRIDE + mq * 16 + g2 * 8);
        const short8 mv = *(const short8*)(As_m + mb * AS_STRIDE + mq * 16 + g2 * 8);
        const short8 lv = *(const short8*)(As_l + mb * AS_STRIDE + mq * 16 + g2 * 8);
#pragma unroll
        for (int j = 0; j < 8; ++j) {
          float v = b2f((unsigned short)hv[j]) + b2f((unsigned short)mv[j]) + b2f((unsigned short)lv[j]);
          ss += v * v;
        }
      }
      red[mb][mq] = ss;
    }
    __syncthreads();  // B2: red complete
    if (tid < 16) {
      float ss = 0.f;
#pragma unroll
      for (int j = 0; j < 16; ++j) ss += red[tid][j];
      maskS[tid] = (ss > 1e-6f) ? 1.0f : 0.0f;
    }
    // gate GEMM K=256, 6-term scheme
    f32x4 a0 = {0.f,0.f,0.f,0.f}, a1 = a0, a2 = a0, a3 = a0, a4 = a0, a5 = a0;
#pragma unroll
    for (int kst = 0; kst < 8; ++kst) {
      const short8 ah = *(const short8*)(As_h + fr * AS_STRIDE + kst * 32 + gq * 8);
      const short8 am = *(const short8*)(As_m + fr * AS_STRIDE + kst * 32 + gq * 8);
      const short8 al = *(const short8*)(As_l + fr * AS_STRIDE + kst * 32 + gq * 8);
      a0 = __builtin_amdgcn_mfma_f32_16x16x32_bf16(ah, dwh[kst], a0, 0, 0, 0);
      a1 = __builtin_amdgcn_mfma_f32_16x16x32_bf16(ah, dwm[kst], a1, 0, 0, 0);
      a2 = __builtin_amdgcn_mfma_f32_16x16x32_bf16(am, dwh[kst], a2, 0, 0, 0);
      a3 = __builtin_amdgcn_mfma_f32_16x16x32_bf16(ah, dwl[kst], a3, 0, 0, 0);
      a4 = __builtin_amdgcn_mfma_f32_16x16x32_bf16(am, dwm[kst], a4, 0, 0, 0);
      a5 = __builtin_amdgcn_mfma_f32_16x16x32_bf16(al, dwh[kst], a5, 0, 0, 0);
    }
    f32x4 d = (((a5 + a4) + a3) + (a2 + a1)) + a0;
#pragma unroll
    for (int i = 0; i < 4; ++i) g_scr[(w * 16 + gq * 4 + i) * 17 + fr] = d[i];
    // rec GEMM on staged h_(t-1): wave w -> kstep pair {2*(w&3), 2*(w&3)+1}
    if (ht < 4) {
      f32x4 r0 = {0.f,0.f,0.f,0.f}, r1 = r0, r2 = r0;
#pragma unroll
      for (int kk = 0; kk < 2; ++kk) {
        const short8 ah = *(const short8*)(As_h + fr * AS_STRIDE + (2 * (w & 3) + kk) * 32 + gq * 8);
        const short8 am = *(const short8*)(As_m + fr * AS_STRIDE + (2 * (w & 3) + kk) * 32 + gq * 8);
        r0 = __builtin_amdgcn_mfma_f32_16x16x32_bf16(ah, rfh[kk], r0, 0, 0, 0);
        r1 = __builtin_amdgcn_mfma_f32_16x16x32_bf16(ah, rfl[kk], r1, 0, 0, 0);
        r2 = __builtin_amdgcn_mfma_f32_16x16x32_bf16(am, rfh[kk], r2, 0, 0, 0);
      }
      f32x4 rd = r0 + r1 + r2;
#pragma unroll
      for (int i = 0; i < 4; ++i) r_scr[(w * 16 + gq * 4 + i) * 17 + fr] = rd[i];
    }
    __syncthreads();  // C
    // cell update + packed-split publish
    {
      const int hsub = (cq >> 4) * 4, fq = cq & 15;
      float gf = g_scr[((0 + hsub) * 16 + cb) * 17 + fq] + bd0;
      float gi = g_scr[((1 + hsub) * 16 + cb) * 17 + fq] + bd1;
      float go = g_scr[((2 + hsub) * 16 + cb) * 17 + fq] + bd2;
      float gc = g_scr[((3 + hsub) * 16 + cb) * 17 + fq] + bd3;
      float m  = maskS[cb];
      float f_ = sigmoidf_(gf), i_ = sigmoidf_(gi), o_ = sigmoidf_(go);
      float ct = tanhf(gc);
      creg = (f_ + i_) * creg + m * (i_ * ct);
      float hval = o_ * tanhf(creg);
      unsigned short hb, mb2, lb;
      bsplit3(hval, hb, mb2, lb);
      u64 pk = ((u64)(unsigned)((s + 1) & 0xffff) << 48) | ((u64)hb << 32) | ((u64)mb2 << 16) | (u64)lb;
      size_t wi = (((size_t)(((s + 1) & 1) * 16 + bt) * 16 + cb) * 256) + hhc;
      __hip_atomic_store(hx + wi, pk, __ATOMIC_RELAXED, __HIP_MEMORY_SCOPE_SYSTEM);
    }
    // reconstruct out[:, t-1, :] (sum the 4 kstep-pair waves of this col-subtile)
    if (ht < 4 && t > 0) {
      const int c2 = cq >> 4, fq = cq & 15;
      float rsum = r_scr[((c2 * 4 + 0) * 16 + cb) * 17 + fq]
                 + r_scr[((c2 * 4 + 1) * 16 + cb) * 17 + fq]
                 + r_scr[((c2 * 4 + 2) * 16 + cb) * 17 + fq]
                 + r_scr[((c2 * 4 + 3) * 16 + cb) * 17 + fq] + recb;
      __builtin_nontemporal_store(rsum, &out[((size_t)(b0 + cb) * kS + (t - 1)) * kI + ht * 32 + cq]);
    }
  }

  // ================= final rec: out[:, 511, :] from h_dec_511 =================
  {
    {
      const u64* grp = hx + ((size_t)(0 * 16 + bt) * 16) * 256;
      u64 u[8];
      pollrow8(grp, col, rbase, (unsigned)((2 * kS) & 0xffff), u);
#pragma unroll
      for (int j = 0; j < 8; ++j) {
        As_h[(rbase + j) * AS_STRIDE + col] = (short)(unsigned short)(u[j] >> 32);
        As_m[(rbase + j) * AS_STRIDE + col] = (short)(unsigned short)(u[j] >> 16);
      }
    }
    __syncthreads();
    if (ht < 4) {
      f32x4 r0 = {0.f,0.f,0.f,0.f}, r1 = r0, r2 = r0;
#pragma unroll
      for (int kk = 0; kk < 2; ++kk) {
        const short8 ah = *(const short8*)(As_h + fr * AS_STRIDE + (2 * (w & 3) + kk) * 32 + gq * 8);
        const short8 am = *(const short8*)(As_m + fr * AS_STRIDE + (2 * (w & 3) + kk) * 32 + gq * 8);
        r0 = __builtin_amdgcn_mfma_f32_16x16x32_bf16(ah, rfh[kk], r0, 0, 0, 0);
        r1 = __builtin_amdgcn_mfma_f32_16x16x32_bf16(ah, rfl[kk], r1, 0, 0, 0);
        r2 = __builtin_amdgcn_mfma_f32_16x16x32_bf16(am, rfh[kk], r2, 0, 0, 0);
      }
      f32x4 rd = r0 + r1 + r2;
#pragma unroll
      for (int i = 0; i < 4; ++i) r_scr[(w * 16 + gq * 4 + i) * 17 + fr] = rd[i];
    }
    __syncthreads();
    if (ht < 4) {
      const int c2 = cq >> 4, fq = cq & 15;
      float rsum = r_scr[((c2 * 4 + 0) * 16 + cb) * 17 + fq]
                 + r_scr[((c2 * 4 + 1) * 16 + cb) * 17 + fq]
                 + r_scr[((c2 * 4 + 2) * 16 + cb) * 17 + fq]
                 + r_scr[((c2 * 4 + 3) * 16 + cb) * 17 + fq] + recb;
      __builtin_nontemporal_store(rsum, &out[((size_t)(b0 + cb) * kS + (kS - 1)) * kI + ht * 32 + cq]);
    }
  }
}

extern "C" void kernel_launch(void* const* d_in, const int* in_sizes, int n_in,
                              void* d_out, int out_size, void* d_ws, size_t ws_size,
                              hipStream_t stream) {
  const float* x      = (const float*)d_in[0];
  const float* enc_Wx = (const float*)d_in[1];
  const float* enc_bx = (const float*)d_in[2];
  const float* enc_Wh = (const float*)d_in[3];
  const float* enc_bh = (const float*)d_in[4];
  const float* enc_b  = (const float*)d_in[5];
  const float* dec_Wx = (const float*)d_in[6];
  const float* dec_bx = (const float*)d_in[7];
  const float* dec_Wh = (const float*)d_in[8];
  const float* dec_bh = (const float*)d_in[9];
  const float* dec_b  = (const float*)d_in[10];
  const float* rec_W  = (const float*)d_in[11];
  const float* rec_b  = (const float*)d_in[12];
  float* out = (float*)d_out;

  u64* hx = (u64*)d_ws;

  // zero hx: seq=0 with zero payload == "h_0 = 0 valid" for the first step
  hipMemsetAsync(d_ws, 0, (size_t)WS_HX_U64 * 8, stream);

  hipLaunchKernelGGL(lstm_mfma, dim3(128), dim3(512), 0, stream,
                     x, enc_Wx, enc_bx, enc_Wh, enc_bh, enc_b,
                     dec_Wx, dec_bx, dec_Wh, dec_bh, dec_b,
                     rec_W, rec_b, out, hx);
}